// Round 2
// baseline (1909.205 us; speedup 1.0000x reference)
//
#include <hip/hip_runtime.h>
#include <hip/hip_bf16.h>

typedef __bf16 bf16x8 __attribute__((ext_vector_type(8)));
typedef float  f32x4  __attribute__((ext_vector_type(4)));
typedef __hip_bfloat16 bf16;
typedef unsigned short u16;
typedef unsigned int   u32;

static constexpr int B_ = 8, T_ = 2048, C_ = 1024, R_ = 64, AR_ = 32, FF_ = 4096;
static constexpr int M_ = B_ * T_;            // 16384 rows
static constexpr int NC_ = 64;                // scan chunks
static constexpr int L_ = T_ / NC_;           // 32 steps per chunk

__device__ __forceinline__ float gelu_tanh(float x) {
    float x3 = x * x * x;
    return 0.5f * x * (1.0f + tanhf(0.7978845608028654f * (x + 0.044715f * x3)));
}

// dual-dtype scalar load: f==1 -> f32, f==0 -> bf16
__device__ __forceinline__ float dual1(const void* p, size_t i, int f) {
    return f ? ((const float*)p)[i] : (float)((const bf16*)p)[i];
}

// ---------------- dtype detector: 1 block. flag=1 if inputs are f32 ----------------
__global__ __launch_bounds__(256) void detect_kernel(const u32* __restrict__ x, int* __restrict__ flag) {
    __shared__ int cnt;
    if (threadIdx.x == 0) cnt = 0;
    __syncthreads();
    u32 u = x[threadIdx.x];
    int e = (u >> 7) & 0xFF;                 // bf16 exponent field if bf16-packed; mantissa bits if f32
    int vote = (e >= 113 && e <= 130) ? 1 : 0;
#pragma unroll
    for (int o = 32; o; o >>= 1) vote += __shfl_down(vote, o);
    if ((threadIdx.x & 63) == 0) atomicAdd(&cnt, vote);
    __syncthreads();
    if (threadIdx.x == 0) flag[0] = (cnt >= 128) ? 0 : 1;   // high hit-rate => bf16
}

// ---------------- batched small-vector convert -> bf16 ----------------
struct VecArgs { const void* s[13]; void* d[13]; int n[13]; };
__global__ __launch_bounds__(256) void vec_convert(VecArgs a, const int* __restrict__ flagp) {
    int f = flagp[0];
    int e = blockIdx.x;
    const void* s = a.s[e];
    bf16* d = (bf16*)a.d[e];
    for (int i = threadIdx.x; i < a.n[e]; i += 256) d[i] = bf16(dual1(s, i, f));
}

// ---------------- transpose+convert (K,N) -> (N,K) bf16 ----------------
__global__ __launch_bounds__(256) void transpose_conv(const void* __restrict__ in, bf16* __restrict__ out,
                                                      int K, int N, const int* __restrict__ flagp) {
    int f = flagp[0];
    __shared__ float tile[32][33];
    int n0 = blockIdx.x * 32, k0 = blockIdx.y * 32;
    int tx = threadIdx.x & 31, ty = threadIdx.x >> 5;
#pragma unroll
    for (int j = 0; j < 4; ++j) {
        int k = k0 + ty + j * 8, n = n0 + tx;
        if (k < K && n < N) tile[ty + j * 8][tx] = dual1(in, (size_t)k * N + n, f);
    }
    __syncthreads();
#pragma unroll
    for (int j = 0; j < 4; ++j) {
        int n = n0 + ty + j * 8, k = k0 + tx;
        if (n < N && k < K) out[(size_t)n * K + k] = bf16(tile[tx][ty + j * 8]);
    }
}

// ---------------- block reduction helper (256 threads = 4 waves) ----------------
__device__ __forceinline__ float2 block_sum2(float a, float b, float2* rbuf, int tid) {
#pragma unroll
    for (int o = 32; o; o >>= 1) { a += __shfl_down(a, o); b += __shfl_down(b, o); }
    if ((tid & 63) == 0) rbuf[tid >> 6] = make_float2(a, b);
    __syncthreads();
    float2 r = make_float2(rbuf[0].x + rbuf[1].x + rbuf[2].x + rbuf[3].x,
                           rbuf[0].y + rbuf[1].y + rbuf[2].y + rbuf[3].y);
    __syncthreads();
    return r;
}

__device__ __forceinline__ void double_ln(float v[4], const bf16* g1, const bf16* b1,
                                          const bf16* g2, const bf16* b2, float2* rbuf, int tid) {
    float s = 0.f, s2 = 0.f;
#pragma unroll
    for (int j = 0; j < 4; ++j) { s += v[j]; s2 += v[j] * v[j]; }
    float2 st = block_sum2(s, s2, rbuf, tid);
    float mu = st.x * (1.0f / C_), var = st.y * (1.0f / C_) - mu * mu, rs = rsqrtf(var + 1e-5f);
#pragma unroll
    for (int j = 0; j < 4; ++j) {
        int c = tid + j * 256;
        v[j] = (v[j] - mu) * rs * (float)g1[c] + (float)b1[c];
    }
    s = 0.f; s2 = 0.f;
#pragma unroll
    for (int j = 0; j < 4; ++j) { s += v[j]; s2 += v[j] * v[j]; }
    st = block_sum2(s, s2, rbuf, tid);
    mu = st.x * (1.0f / C_); var = st.y * (1.0f / C_) - mu * mu; rs = rsqrtf(var + 1e-5f);
#pragma unroll
    for (int j = 0; j < 4; ++j) {
        int c = tid + j * 256;
        v[j] = (v[j] - mu) * rs * (float)g2[c] + (float)b2[c];
    }
}

// ---------------- fused double-LN + token-shift mix (xn never materialized) ----------------
__global__ __launch_bounds__(256) void ln_mix_kernel(const void* __restrict__ x, const int* __restrict__ flagp,
                                                     const bf16* __restrict__ g1, const bf16* __restrict__ b1,
                                                     const bf16* __restrict__ g2, const bf16* __restrict__ b2,
                                                     bf16* __restrict__ mix) {
    __shared__ float2 rbuf[4];
    int row = blockIdx.x, tid = threadIdx.x;
    int t = row % T_;
    int f = flagp[0];
    float cur[4];
#pragma unroll
    for (int j = 0; j < 4; ++j) cur[j] = dual1(x, (size_t)row * C_ + tid + j * 256, f);
    double_ln(cur, g1, b1, g2, b2, rbuf, tid);
    float prv[4] = {0.f, 0.f, 0.f, 0.f};
    if (t > 0) {                                   // block-uniform branch (barriers inside are safe)
#pragma unroll
        for (int j = 0; j < 4; ++j) prv[j] = dual1(x, (size_t)(row - 1) * C_ + tid + j * 256, f);
        double_ln(prv, g1, b1, g2, b2, rbuf, tid);
    }
#pragma unroll
    for (int j = 0; j < 4; ++j)
        mix[(size_t)row * C_ + tid + j * 256] = bf16(0.5f * (cur[j] + prv[j]));
}

// ---------------- single layernorm on f32 residual -> bf16 ----------------
__global__ __launch_bounds__(256) void ln_single_kernel(const float* __restrict__ x,
                                                        const bf16* __restrict__ g, const bf16* __restrict__ b,
                                                        bf16* __restrict__ out) {
    __shared__ float2 rbuf[4];
    int row = blockIdx.x, tid = threadIdx.x;
    float v[4];
#pragma unroll
    for (int j = 0; j < 4; ++j) v[j] = x[(size_t)row * C_ + tid + j * 256];
    float s = 0.f, s2 = 0.f;
#pragma unroll
    for (int j = 0; j < 4; ++j) { s += v[j]; s2 += v[j] * v[j]; }
    float2 st = block_sum2(s, s2, rbuf, tid);
    float mu = st.x * (1.0f / C_), var = st.y * (1.0f / C_) - mu * mu, rs = rsqrtf(var + 1e-5f);
#pragma unroll
    for (int j = 0; j < 4; ++j) {
        int c = tid + j * 256;
        out[(size_t)row * C_ + c] = bf16((v[j] - mu) * rs * (float)g[c] + (float)b[c]);
    }
}

// ---------------- chunked linear recurrence: h = d*h + k*v ; y = sigmoid(q)*h ----------------
__global__ __launch_bounds__(256) void scan_pass1(const bf16* __restrict__ kb, const bf16* __restrict__ vb,
                                                  const bf16* __restrict__ td, float* __restrict__ carry) {
    int cb = blockIdx.x & 3;
    int chunk = (blockIdx.x >> 2) & (NC_ - 1);
    int b = blockIdx.x >> 8;
    int c = cb * 256 + threadIdx.x;
    float d = expf(-expf((float)td[c]));
    float h = 0.f;
    size_t base = ((size_t)b * T_ + (size_t)chunk * L_) * C_ + c;
#pragma unroll 4
    for (int j = 0; j < L_; ++j) {
        float kk = (float)kb[base + (size_t)j * C_];
        float vv = (float)vb[base + (size_t)j * C_];
        h = d * h + kk * vv;
    }
    carry[((size_t)(b * NC_ + chunk)) * C_ + c] = h;
}

__global__ __launch_bounds__(256) void scan_combine(const float* __restrict__ carry, float* __restrict__ hin,
                                                    const bf16* __restrict__ h0b, const bf16* __restrict__ td,
                                                    void* __restrict__ dout, const int* __restrict__ flagp) {
    int f = flagp[0];
    int cb = blockIdx.x & 3;
    int b = blockIdx.x >> 2;
    int c = cb * 256 + threadIdx.x;
    float d = expf(-expf((float)td[c]));
    float dL = powf(d, (float)L_);
    float run = (float)h0b[(size_t)b * C_ + c];
    for (int i = 0; i < NC_; ++i) {
        size_t o = ((size_t)(b * NC_ + i)) * C_ + c;
        hin[o] = run;
        run = dL * run + carry[o];
    }
    size_t oo = (size_t)B_ * T_ * C_ + (size_t)b * C_ + c;   // h_final after x in d_out
    if (f) ((float*)dout)[oo] = run; else ((bf16*)dout)[oo] = bf16(run);
}

// writes ys IN PLACE over qb (read-before-write per element, same thread)
__global__ __launch_bounds__(256) void scan_pass2(bf16* __restrict__ qb, const bf16* __restrict__ kb,
                                                  const bf16* __restrict__ vb, const bf16* __restrict__ td,
                                                  const float* __restrict__ hin) {
    int cb = blockIdx.x & 3;
    int chunk = (blockIdx.x >> 2) & (NC_ - 1);
    int b = blockIdx.x >> 8;
    int c = cb * 256 + threadIdx.x;
    float d = expf(-expf((float)td[c]));
    float h = hin[((size_t)(b * NC_ + chunk)) * C_ + c];
    size_t base = ((size_t)b * T_ + (size_t)chunk * L_) * C_ + c;
#pragma unroll 4
    for (int j = 0; j < L_; ++j) {
        size_t o = base + (size_t)j * C_;
        float kk = (float)kb[o], vv = (float)vb[o], qq = (float)qb[o];
        h = d * h + kk * vv;
        float sg = 1.0f / (1.0f + expf(-qq));
        qb[o] = bf16(sg * h);
    }
}

// ---------------- bf16 MFMA GEMM: C[M,N] = A[M,K] @ B (BT given as N x K) ----------------
// BIAS: 0/1 (bf16[N]).  ACT: 0 none, 1 gelu.
// RES: 0 none, 2 f32 ws, 3 dual(flag: f32 or bf16).
// OUTM: 0 bf16, 1 f32, 2 f32 out0 + bf16 out1, 3 dual(flag) to d_out.
template <int BM, int BN, int BK, int WM, int WN, int BIAS, int ACT, int RES, int OUTM>
__global__ __launch_bounds__(256) void gemm_bt(const bf16* __restrict__ A, const bf16* __restrict__ BT,
                                               const bf16* __restrict__ bias, const void* __restrict__ res,
                                               void* __restrict__ out0, void* __restrict__ out1,
                                               int M, int N, int K, const int* __restrict__ flagp) {
    constexpr int LDA = BK + 8;
    constexpr int WGM = BM / WM;
    constexpr int MT = WM / 16, NT = WN / 16;
    constexpr int KC = BK / 8;
    constexpr int CHA = BM * KC, CHB = BN * KC;
    constexpr int RA = (CHA + 255) / 256, RB = (CHB + 255) / 256;
    static_assert(WGM * (BN / WN) == 4, "4 waves");
    __shared__ u16 sA[BM * LDA];
    __shared__ u16 sB[BN * LDA];
    const int tid = threadIdx.x, lane = tid & 63, wid = tid >> 6;
    const int wm = wid % WGM, wn = wid / WGM;
    const int l15 = lane & 15, lq = lane >> 4;
    const size_t m0 = (size_t)blockIdx.x * BM, n0 = (size_t)blockIdx.y * BN;
    const int KT = K / BK;
    const int f32f = (RES == 3 || OUTM == 3) ? flagp[0] : 0;

    uint4 ra[RA], rb[RB];
    auto gload = [&](int kt) {
#pragma unroll
        for (int i = 0; i < RA; ++i) {
            int ci = tid + i * 256;
            if ((CHA % 256 == 0) || ci < CHA) {
                int r = ci / KC, kc = ci % KC;
                ra[i] = *(const uint4*)((const u16*)A + (m0 + r) * (size_t)K + (size_t)kt * BK + kc * 8);
            }
        }
#pragma unroll
        for (int i = 0; i < RB; ++i) {
            int ci = tid + i * 256;
            if ((CHB % 256 == 0) || ci < CHB) {
                int r = ci / KC, kc = ci % KC;
                rb[i] = *(const uint4*)((const u16*)BT + (n0 + r) * (size_t)K + (size_t)kt * BK + kc * 8);
            }
        }
    };
    auto lstore = [&]() {
#pragma unroll
        for (int i = 0; i < RA; ++i) {
            int ci = tid + i * 256;
            if ((CHA % 256 == 0) || ci < CHA) {
                int r = ci / KC, kc = ci % KC;
                *(uint4*)&sA[r * LDA + kc * 8] = ra[i];
            }
        }
#pragma unroll
        for (int i = 0; i < RB; ++i) {
            int ci = tid + i * 256;
            if ((CHB % 256 == 0) || ci < CHB) {
                int r = ci / KC, kc = ci % KC;
                *(uint4*)&sB[r * LDA + kc * 8] = rb[i];
            }
        }
    };

    f32x4 acc[MT][NT];
#pragma unroll
    for (int i = 0; i < MT; ++i)
#pragma unroll
        for (int j = 0; j < NT; ++j) acc[i][j] = 0.0f;

    gload(0);
    for (int kt = 0; kt < KT; ++kt) {
        __syncthreads();
        lstore();
        if (kt + 1 < KT) gload(kt + 1);
        __syncthreads();
        bf16x8 af[MT], bfr[NT];
#pragma unroll
        for (int i = 0; i < MT; ++i)
            af[i] = *(const bf16x8*)&sA[(wm * WM + i * 16 + l15) * LDA + 8 * lq];
#pragma unroll
        for (int j = 0; j < NT; ++j)
            bfr[j] = *(const bf16x8*)&sB[(wn * WN + j * 16 + l15) * LDA + 8 * lq];
#pragma unroll
        for (int i = 0; i < MT; ++i)
#pragma unroll
            for (int j = 0; j < NT; ++j)
                acc[i][j] = __builtin_amdgcn_mfma_f32_16x16x32_bf16(af[i], bfr[j], acc[i][j], 0, 0, 0);
    }

    // epilogue: D[row = 4*lq + r][col = l15] per 16x16 tile
#pragma unroll
    for (int i = 0; i < MT; ++i) {
#pragma unroll
        for (int j = 0; j < NT; ++j) {
            size_t gn = n0 + wn * WN + j * 16 + l15;
            float bv = 0.f;
            if constexpr (BIAS) bv = (float)bias[gn];
#pragma unroll
            for (int r = 0; r < 4; ++r) {
                size_t gm = m0 + wm * WM + i * 16 + 4 * lq + r;
                float v = acc[i][j][r] + bv;
                if constexpr (ACT == 1) v = gelu_tanh(v);
                size_t o = gm * (size_t)N + gn;
                if constexpr (RES == 2) v += ((const float*)res)[o];
                if constexpr (RES == 3) v += f32f ? ((const float*)res)[o] : (float)((const bf16*)res)[o];
                if constexpr (OUTM == 0) ((bf16*)out0)[o] = bf16(v);
                else if constexpr (OUTM == 1) ((float*)out0)[o] = v;
                else if constexpr (OUTM == 2) { ((float*)out0)[o] = v; ((bf16*)out1)[o] = bf16(v); }
                else { if (f32f) ((float*)out0)[o] = v; else ((bf16*)out0)[o] = bf16(v); }
            }
        }
    }
}

// ---------------- host side ----------------
extern "C" void kernel_launch(void* const* d_in, const int* in_sizes, int n_in,
                              void* d_out, int out_size, void* d_ws, size_t ws_size,
                              hipStream_t stream) {
    (void)in_sizes; (void)n_in; (void)out_size;
    const void* x     = d_in[0];
    const void* h0    = d_in[1];
    const void* ln1_g = d_in[2];
    const void* ln1_b = d_in[3];
    const void* tm_g  = d_in[4];
    const void* tm_b  = d_in[5];
    const void* qu    = d_in[6];
    const void* qv    = d_in[7];
    const void* ku    = d_in[8];
    const void* kv    = d_in[9];
    const void* vu    = d_in[10];
    const void* vv    = d_in[11];
    const void* td    = d_in[12];
    const void* out_w = d_in[13];
    const void* out_b = d_in[14];
    const void* ln2_g = d_in[15];
    const void* ln2_b = d_in[16];
    const void* ffn_w1 = d_in[17];
    const void* ffn_b1 = d_in[18];
    const void* ffn_w2 = d_in[19];
    const void* ffn_b2 = d_in[20];
    const void* ad_w  = d_in[21];
    const void* ad_b  = d_in[22];
    const void* au_w  = d_in[23];
    const void* au_b  = d_in[24];

    char* ws = (char*)d_ws;
    size_t off = 0;
    auto alloc = [&](size_t bytes) -> void* {
        void* p = ws + off;
        off += (bytes + 255) & ~(size_t)255;
        return p;
    };
    const size_t BTC = (size_t)B_ * T_ * C_;
    // converted weights (N x K bf16)
    bf16* quT = (bf16*)alloc((size_t)C_ * R_ * 2);
    bf16* kuT = (bf16*)alloc((size_t)C_ * R_ * 2);
    bf16* vuT = (bf16*)alloc((size_t)C_ * R_ * 2);
    bf16* qvT = (bf16*)alloc((size_t)C_ * R_ * 2);
    bf16* kvT = (bf16*)alloc((size_t)C_ * R_ * 2);
    bf16* vvT = (bf16*)alloc((size_t)C_ * R_ * 2);
    bf16* owT = (bf16*)alloc((size_t)C_ * C_ * 2);
    bf16* w1T = (bf16*)alloc((size_t)C_ * FF_ * 2);
    bf16* w2T = (bf16*)alloc((size_t)C_ * FF_ * 2);
    bf16* adT = (bf16*)alloc((size_t)C_ * AR_ * 2);
    bf16* auT = (bf16*)alloc((size_t)C_ * AR_ * 2);
    // converted small vectors (bf16)
    bf16* c_ln1g = (bf16*)alloc(C_ * 2);
    bf16* c_ln1b = (bf16*)alloc(C_ * 2);
    bf16* c_tmg  = (bf16*)alloc(C_ * 2);
    bf16* c_tmb  = (bf16*)alloc(C_ * 2);
    bf16* c_td   = (bf16*)alloc(C_ * 2);
    bf16* c_outb = (bf16*)alloc(C_ * 2);
    bf16* c_ln2g = (bf16*)alloc(C_ * 2);
    bf16* c_ln2b = (bf16*)alloc(C_ * 2);
    bf16* c_fb1  = (bf16*)alloc(FF_ * 2);
    bf16* c_fb2  = (bf16*)alloc(C_ * 2);
    bf16* c_adb  = (bf16*)alloc(AR_ * 2);
    bf16* c_aub  = (bf16*)alloc(C_ * 2);
    bf16* c_h0   = (bf16*)alloc((size_t)B_ * C_ * 2);
    int*  flag   = (int*)alloc(256);
    // activations: [mixb][vb] contiguous so x1f (f32, 64MB) can alias both later
    bf16* mixb = (bf16*)alloc(BTC * 2);
    bf16* vb   = (bf16*)alloc(BTC * 2);
    bf16* qb   = (bf16*)alloc(BTC * 2);   // q -> ys (in place) -> (chunked) ffn mid
    bf16* kb   = (bf16*)alloc(BTC * 2);   // k -> h2n -> x2b (in place per chunk)
    bf16* tq   = (bf16*)alloc((size_t)M_ * R_ * 2);
    float* carry = (float*)alloc((size_t)B_ * NC_ * C_ * 4);
    float* hin   = (float*)alloc((size_t)B_ * NC_ * C_ * 4);
    float* x1f = (float*)mixb;            // aliases mixb+vb (both dead by then)

    const size_t midb_bytes = (size_t)M_ * FF_ * 2;
    bool big = ws_size >= off + midb_bytes + (1u << 20);
    bf16* midb = big ? (bf16*)alloc(midb_bytes) : qb;
    const int nchunk = big ? 1 : 4;
    const int crows = M_ / nchunk;

    detect_kernel<<<1, 256, 0, stream>>>((const u32*)x, flag);

    VecArgs va;
    const void* vs[13] = {ln1_g, ln1_b, tm_g, tm_b, td, out_b, ln2_g, ln2_b, ffn_b1, ffn_b2, ad_b, au_b, h0};
    void* vd[13] = {c_ln1g, c_ln1b, c_tmg, c_tmb, c_td, c_outb, c_ln2g, c_ln2b, c_fb1, c_fb2, c_adb, c_aub, c_h0};
    int vn[13] = {C_, C_, C_, C_, C_, C_, C_, C_, FF_, C_, AR_, C_, B_ * C_};
    for (int i = 0; i < 13; ++i) { va.s[i] = vs[i]; va.d[i] = vd[i]; va.n[i] = vn[i]; }
    vec_convert<<<13, 256, 0, stream>>>(va, flag);

    auto tlaunch = [&](const void* in, bf16* out, int K, int N) {
        transpose_conv<<<dim3((N + 31) / 32, (K + 31) / 32), 256, 0, stream>>>(in, out, K, N, flag);
    };
    tlaunch(qu, quT, C_, R_);
    tlaunch(ku, kuT, C_, R_);
    tlaunch(vu, vuT, C_, R_);
    tlaunch(qv, qvT, R_, C_);
    tlaunch(kv, kvT, R_, C_);
    tlaunch(vv, vvT, R_, C_);
    tlaunch(out_w, owT, C_, C_);
    tlaunch(ffn_w1, w1T, C_, FF_);
    tlaunch(ffn_w2, w2T, FF_, C_);
    tlaunch(ad_w, adT, C_, AR_);
    tlaunch(au_w, auT, AR_, C_);

    ln_mix_kernel<<<M_, 256, 0, stream>>>(x, flag, c_ln1g, c_ln1b, c_tmg, c_tmb, mixb);

    // low-rank projections: (mix @ u) @ v  for q, k, v
    gemm_bt<64, 64, 32, 32, 32, 0, 0, 0, 0><<<dim3(M_ / 64, 1), 256, 0, stream>>>(
        mixb, quT, nullptr, nullptr, tq, nullptr, M_, R_, C_, flag);
    gemm_bt<128, 128, 32, 64, 64, 0, 0, 0, 0><<<dim3(M_ / 128, C_ / 128), 256, 0, stream>>>(
        tq, qvT, nullptr, nullptr, qb, nullptr, M_, C_, R_, flag);
    gemm_bt<64, 64, 32, 32, 32, 0, 0, 0, 0><<<dim3(M_ / 64, 1), 256, 0, stream>>>(
        mixb, kuT, nullptr, nullptr, tq, nullptr, M_, R_, C_, flag);
    gemm_bt<128, 128, 32, 64, 64, 0, 0, 0, 0><<<dim3(M_ / 128, C_ / 128), 256, 0, stream>>>(
        tq, kvT, nullptr, nullptr, kb, nullptr, M_, C_, R_, flag);
    gemm_bt<64, 64, 32, 32, 32, 0, 0, 0, 0><<<dim3(M_ / 64, 1), 256, 0, stream>>>(
        mixb, vuT, nullptr, nullptr, tq, nullptr, M_, R_, C_, flag);
    gemm_bt<128, 128, 32, 64, 64, 0, 0, 0, 0><<<dim3(M_ / 128, C_ / 128), 256, 0, stream>>>(
        tq, vvT, nullptr, nullptr, vb, nullptr, M_, C_, R_, flag);

    // chunked linear recurrence (h_final written to d_out inside scan_combine)
    scan_pass1<<<B_ * NC_ * (C_ / 256), 256, 0, stream>>>(kb, vb, c_td, carry);
    scan_combine<<<B_ * (C_ / 256), 256, 0, stream>>>(carry, hin, c_h0, c_td, d_out, flag);
    scan_pass2<<<B_ * NC_ * (C_ / 256), 256, 0, stream>>>(qb, kb, vb, c_td, hin);

    // attn out projection + residual(x, dual dtype) -> x1f (f32; aliases mixb+vb)
    gemm_bt<128, 128, 32, 64, 64, 1, 0, 3, 1><<<dim3(M_ / 128, C_ / 128), 256, 0, stream>>>(
        qb, owT, c_outb, x, x1f, nullptr, M_, C_, C_, flag);

    // FFN (chunked over rows if workspace is tight; midb reuses qb then)
    ln_single_kernel<<<M_, 256, 0, stream>>>(x1f, c_ln2g, c_ln2b, kb);
    for (int c = 0; c < nchunk; ++c) {
        bf16* h2c = kb + (size_t)c * crows * C_;
        bf16* mid = big ? midb + (size_t)c * crows * FF_ : midb;
        float* x1c = x1f + (size_t)c * crows * C_;
        gemm_bt<128, 128, 32, 64, 64, 1, 1, 0, 0><<<dim3(crows / 128, FF_ / 128), 256, 0, stream>>>(
            h2c, w1T, c_fb1, nullptr, mid, nullptr, crows, FF_, C_, flag);
        gemm_bt<128, 128, 32, 64, 64, 1, 0, 2, 2><<<dim3(crows / 128, C_ / 128), 256, 0, stream>>>(
            mid, w2T, c_fb2, x1c, x1c, h2c, crows, C_, FF_, flag);
    }

    // adapter: x2b lives in kb (fully rewritten by ffn2 chunks)
    gemm_bt<64, 32, 32, 32, 16, 1, 1, 0, 0><<<dim3(M_ / 64, 1), 256, 0, stream>>>(
        kb, adT, c_adb, nullptr, tq, nullptr, M_, AR_, C_, flag);
    gemm_bt<128, 128, 32, 64, 64, 1, 0, 2, 3><<<dim3(M_ / 128, C_ / 128), 256, 0, stream>>>(
        tq, auT, c_aub, x1f, d_out, nullptr, M_, C_, AR_, flag);
}

// Round 3
// 1836.032 us; speedup vs baseline: 1.0399x; 1.0399x over previous
//
#include <hip/hip_runtime.h>
#include <hip/hip_bf16.h>

typedef __bf16 bf16x8 __attribute__((ext_vector_type(8)));
typedef float  f32x4  __attribute__((ext_vector_type(4)));
typedef __hip_bfloat16 bf16;
typedef unsigned short u16;
typedef unsigned int   u32;

static constexpr int B_ = 8, T_ = 2048, C_ = 1024, R_ = 64, AR_ = 32, FF_ = 4096;
static constexpr int M_ = B_ * T_;
static constexpr int NC_ = 64;                // scan chunks
static constexpr int L_ = T_ / NC_;           // 32 steps per chunk

__device__ __forceinline__ float gelu_tanh(float x) {
    float x3 = x * x * x;
    return 0.5f * x * (1.0f + tanhf(0.7978845608028654f * (x + 0.044715f * x3)));
}
__device__ __forceinline__ float dual1(const void* p, size_t i, int f) {
    return f ? ((const float*)p)[i] : (float)((const bf16*)p)[i];
}

// ---------------- dtype detector: flag=1 if inputs are f32 ----------------
__global__ __launch_bounds__(256) void detect_kernel(const u32* __restrict__ x, int* __restrict__ flag) {
    __shared__ int cnt;
    if (threadIdx.x == 0) cnt = 0;
    __syncthreads();
    u32 u = x[threadIdx.x];
    int e = (u >> 7) & 0xFF;
    int vote = (e >= 113 && e <= 130) ? 1 : 0;
#pragma unroll
    for (int o = 32; o; o >>= 1) vote += __shfl_down(vote, o);
    if ((threadIdx.x & 63) == 0) atomicAdd(&cnt, vote);
    __syncthreads();
    if (threadIdx.x == 0) flag[0] = (cnt >= 128) ? 0 : 1;
}

// ---------------- single weight-prep kernel: 11 transposes + 13 vec converts ----------------
struct PrepArgs {
    const void* src[24];
    void* dst[24];
    int K[24], N[24];
    int start[26];
    int n_tr;
};
__global__ __launch_bounds__(256) void weight_prep(PrepArgs a, const int* __restrict__ flagp) {
    __shared__ float tile[32][33];
    int f = flagp[0];
    int bid = blockIdx.x;
    int t = 0;
    while (bid >= a.start[t + 1]) ++t;
    int local = bid - a.start[t];
    if (t < a.n_tr) {
        int K = a.K[t], N = a.N[t];
        int nbx = (N + 31) >> 5;
        int bx = local % nbx, by = local / nbx;
        int n0 = bx * 32, k0 = by * 32;
        int tx = threadIdx.x & 31, ty = threadIdx.x >> 5;
        const void* in = a.src[t];
        bf16* out = (bf16*)a.dst[t];
#pragma unroll
        for (int j = 0; j < 4; ++j) {
            int k = k0 + ty + j * 8, n = n0 + tx;
            if (k < K && n < N) tile[ty + j * 8][tx] = dual1(in, (size_t)k * N + n, f);
        }
        __syncthreads();
#pragma unroll
        for (int j = 0; j < 4; ++j) {
            int n = n0 + ty + j * 8, k = k0 + tx;
            if (n < N && k < K) out[(size_t)n * K + k] = bf16(tile[tx][ty + j * 8]);
        }
    } else {
        const void* s = a.src[t];
        bf16* d = (bf16*)a.dst[t];
        for (int i = threadIdx.x; i < a.N[t]; i += 256) d[i] = bf16(dual1(s, i, f));
    }
}

// ---------------- block reduction helper ----------------
__device__ __forceinline__ float2 block_sum2(float a, float b, float2* rbuf, int tid) {
#pragma unroll
    for (int o = 32; o; o >>= 1) { a += __shfl_down(a, o); b += __shfl_down(b, o); }
    if ((tid & 63) == 0) rbuf[tid >> 6] = make_float2(a, b);
    __syncthreads();
    float2 r = make_float2(rbuf[0].x + rbuf[1].x + rbuf[2].x + rbuf[3].x,
                           rbuf[0].y + rbuf[1].y + rbuf[2].y + rbuf[3].y);
    __syncthreads();
    return r;
}

// ---------------- double layernorm -> xn (bf16) ----------------
__global__ __launch_bounds__(256) void ln2x_kernel(const void* __restrict__ x, const int* __restrict__ flagp,
                                                   const bf16* __restrict__ g1, const bf16* __restrict__ b1,
                                                   const bf16* __restrict__ g2, const bf16* __restrict__ b2,
                                                   bf16* __restrict__ xn) {
    __shared__ float2 rbuf[4];
    int row = blockIdx.x, tid = threadIdx.x;
    int f = flagp[0];
    float v[4];
#pragma unroll
    for (int j = 0; j < 4; ++j) v[j] = dual1(x, (size_t)row * C_ + tid + j * 256, f);
    float s = 0.f, s2 = 0.f;
#pragma unroll
    for (int j = 0; j < 4; ++j) { s += v[j]; s2 += v[j] * v[j]; }
    float2 st = block_sum2(s, s2, rbuf, tid);
    float mu = st.x * (1.0f / C_), var = st.y * (1.0f / C_) - mu * mu, rs = rsqrtf(var + 1e-5f);
#pragma unroll
    for (int j = 0; j < 4; ++j) {
        int c = tid + j * 256;
        v[j] = (v[j] - mu) * rs * (float)g1[c] + (float)b1[c];
    }
    s = 0.f; s2 = 0.f;
#pragma unroll
    for (int j = 0; j < 4; ++j) { s += v[j]; s2 += v[j] * v[j]; }
    st = block_sum2(s, s2, rbuf, tid);
    mu = st.x * (1.0f / C_); var = st.y * (1.0f / C_) - mu * mu; rs = rsqrtf(var + 1e-5f);
#pragma unroll
    for (int j = 0; j < 4; ++j) {
        int c = tid + j * 256;
        xn[(size_t)row * C_ + c] = bf16((v[j] - mu) * rs * (float)g2[c] + (float)b2[c]);
    }
}

// ---------------- single layernorm on f32 residual -> bf16 ----------------
__global__ __launch_bounds__(256) void ln_single_kernel(const float* __restrict__ x,
                                                        const bf16* __restrict__ g, const bf16* __restrict__ b,
                                                        bf16* __restrict__ out) {
    __shared__ float2 rbuf[4];
    int row = blockIdx.x, tid = threadIdx.x;
    float v[4];
#pragma unroll
    for (int j = 0; j < 4; ++j) v[j] = x[(size_t)row * C_ + tid + j * 256];
    float s = 0.f, s2 = 0.f;
#pragma unroll
    for (int j = 0; j < 4; ++j) { s += v[j]; s2 += v[j] * v[j]; }
    float2 st = block_sum2(s, s2, rbuf, tid);
    float mu = st.x * (1.0f / C_), var = st.y * (1.0f / C_) - mu * mu, rs = rsqrtf(var + 1e-5f);
#pragma unroll
    for (int j = 0; j < 4; ++j) {
        int c = tid + j * 256;
        out[(size_t)row * C_ + c] = bf16((v[j] - mu) * rs * (float)g[c] + (float)b[c]);
    }
}

// ---------------- chunked linear recurrence ----------------
__global__ __launch_bounds__(256) void scan_pass1(const bf16* __restrict__ kb, const bf16* __restrict__ vb,
                                                  const bf16* __restrict__ td, float* __restrict__ carry) {
    int cb = blockIdx.x & 3;
    int chunk = (blockIdx.x >> 2) & (NC_ - 1);
    int b = blockIdx.x >> 8;
    int c = cb * 256 + threadIdx.x;
    float d = expf(-expf((float)td[c]));
    float h = 0.f;
    size_t base = ((size_t)b * T_ + (size_t)chunk * L_) * C_ + c;
#pragma unroll 4
    for (int j = 0; j < L_; ++j) {
        float kk = (float)kb[base + (size_t)j * C_];
        float vv = (float)vb[base + (size_t)j * C_];
        h = d * h + kk * vv;
    }
    carry[((size_t)(b * NC_ + chunk)) * C_ + c] = h;
}

__global__ __launch_bounds__(256) void scan_combine(const float* __restrict__ carry, float* __restrict__ hin,
                                                    const bf16* __restrict__ h0b, const bf16* __restrict__ td,
                                                    void* __restrict__ dout, const int* __restrict__ flagp) {
    int f = flagp[0];
    int cb = blockIdx.x & 3;
    int b = blockIdx.x >> 2;
    int c = cb * 256 + threadIdx.x;
    float d = expf(-expf((float)td[c]));
    float dL = powf(d, (float)L_);
    float run = (float)h0b[(size_t)b * C_ + c];
    for (int i = 0; i < NC_; ++i) {
        size_t o = ((size_t)(b * NC_ + i)) * C_ + c;
        hin[o] = run;
        run = dL * run + carry[o];
    }
    size_t oo = (size_t)B_ * T_ * C_ + (size_t)b * C_ + c;
    if (f) ((float*)dout)[oo] = run; else ((bf16*)dout)[oo] = bf16(run);
}

__global__ __launch_bounds__(256) void scan_pass2(bf16* __restrict__ qb, const bf16* __restrict__ kb,
                                                  const bf16* __restrict__ vb, const bf16* __restrict__ td,
                                                  const float* __restrict__ hin) {
    int cb = blockIdx.x & 3;
    int chunk = (blockIdx.x >> 2) & (NC_ - 1);
    int b = blockIdx.x >> 8;
    int c = cb * 256 + threadIdx.x;
    float d = expf(-expf((float)td[c]));
    float h = hin[((size_t)(b * NC_ + chunk)) * C_ + c];
    size_t base = ((size_t)b * T_ + (size_t)chunk * L_) * C_ + c;
#pragma unroll 4
    for (int j = 0; j < L_; ++j) {
        size_t o = base + (size_t)j * C_;
        float kk = (float)kb[o], vv = (float)vb[o], qq = (float)qb[o];
        h = d * h + kk * vv;
        float sg = 1.0f / (1.0f + expf(-qq));
        qb[o] = bf16(sg * h);
    }
}

// ---------------- bf16 MFMA GEMM core (device fn; named wrappers below) ----------------
// A is M x K with row stride lda. BT is N x K. AMIX: A-load averages rows gm,gm-1 (token shift).
// RES: 0 none, 2 f32, 3 dual(flag). OUTM: 0 bf16, 1 f32, 2 f32 out0 + bf16 out1, 3 dual(flag).
template <int BM, int BN, int BK, int WM, int WN, int BIAS, int ACT, int RES, int OUTM, int AMIX>
__device__ __forceinline__ void gemm_core(const bf16* __restrict__ A, int lda, const bf16* __restrict__ BT,
                                          const bf16* __restrict__ bias, const void* __restrict__ res,
                                          void* __restrict__ out0, void* __restrict__ out1,
                                          int M, int N, int K, const int* __restrict__ flagp) {
    constexpr int LDA = BK + 8;
    constexpr int WGM = BM / WM;
    constexpr int MT = WM / 16, NT = WN / 16;
    constexpr int KC = BK / 8;
    constexpr int CHA = BM * KC, CHB = BN * KC;
    constexpr int RA = (CHA + 255) / 256, RB = (CHB + 255) / 256;
    static_assert(WGM * (BN / WN) == 4, "4 waves");
    __shared__ u16 sA[BM * LDA];
    __shared__ u16 sB[BN * LDA];
    const int tid = threadIdx.x, lane = tid & 63, wid = tid >> 6;
    const int wm = wid % WGM, wn = wid / WGM;
    const int l15 = lane & 15, lq = lane >> 4;
    const size_t m0 = (size_t)blockIdx.x * BM, n0 = (size_t)blockIdx.y * BN;
    const int KT = K / BK;
    const int f32f = (RES == 3 || OUTM == 3) ? flagp[0] : 0;

    uint4 ra[RA], rb[RB];
    auto gload = [&](int kt) {
#pragma unroll
        for (int i = 0; i < RA; ++i) {
            int ci = tid + i * 256;
            if ((CHA % 256 == 0) || ci < CHA) {
                int r = ci / KC, kc = ci % KC;
                const u16* gp = (const u16*)A + (m0 + r) * (size_t)lda + (size_t)kt * BK + kc * 8;
                if constexpr (AMIX) {
                    uint4 c0 = *(const uint4*)gp;
                    uint4 p0 = make_uint4(0, 0, 0, 0);
                    if ((int)((m0 + r) % T_) != 0) p0 = *(const uint4*)(gp - lda);
                    bf16 cc[8], pp[8], oo[8];
                    *(uint4*)cc = c0; *(uint4*)pp = p0;
#pragma unroll
                    for (int j = 0; j < 8; ++j) oo[j] = bf16(0.5f * ((float)cc[j] + (float)pp[j]));
                    ra[i] = *(uint4*)oo;
                } else {
                    ra[i] = *(const uint4*)gp;
                }
            }
        }
#pragma unroll
        for (int i = 0; i < RB; ++i) {
            int ci = tid + i * 256;
            if ((CHB % 256 == 0) || ci < CHB) {
                int r = ci / KC, kc = ci % KC;
                rb[i] = *(const uint4*)((const u16*)BT + (n0 + r) * (size_t)K + (size_t)kt * BK + kc * 8);
            }
        }
    };
    auto lstore = [&]() {
#pragma unroll
        for (int i = 0; i < RA; ++i) {
            int ci = tid + i * 256;
            if ((CHA % 256 == 0) || ci < CHA) {
                int r = ci / KC, kc = ci % KC;
                *(uint4*)&sA[r * LDA + kc * 8] = ra[i];
            }
        }
#pragma unroll
        for (int i = 0; i < RB; ++i) {
            int ci = tid + i * 256;
            if ((CHB % 256 == 0) || ci < CHB) {
                int r = ci / KC, kc = ci % KC;
                *(uint4*)&sB[r * LDA + kc * 8] = rb[i];
            }
        }
    };

    f32x4 acc[MT][NT];
#pragma unroll
    for (int i = 0; i < MT; ++i)
#pragma unroll
        for (int j = 0; j < NT; ++j) acc[i][j] = 0.0f;

    gload(0);
    for (int kt = 0; kt < KT; ++kt) {
        __syncthreads();
        lstore();
        if (kt + 1 < KT) gload(kt + 1);
        __syncthreads();
        bf16x8 af[MT], bfr[NT];
#pragma unroll
        for (int i = 0; i < MT; ++i)
            af[i] = *(const bf16x8*)&sA[(wm * WM + i * 16 + l15) * LDA + 8 * lq];
#pragma unroll
        for (int j = 0; j < NT; ++j)
            bfr[j] = *(const bf16x8*)&sB[(wn * WN + j * 16 + l15) * LDA + 8 * lq];
#pragma unroll
        for (int i = 0; i < MT; ++i)
#pragma unroll
            for (int j = 0; j < NT; ++j)
                acc[i][j] = __builtin_amdgcn_mfma_f32_16x16x32_bf16(af[i], bfr[j], acc[i][j], 0, 0, 0);
    }

#pragma unroll
    for (int i = 0; i < MT; ++i) {
#pragma unroll
        for (int j = 0; j < NT; ++j) {
            size_t gn = n0 + wn * WN + j * 16 + l15;
            float bv = 0.f;
            if constexpr (BIAS) bv = (float)bias[gn];
#pragma unroll
            for (int r = 0; r < 4; ++r) {
                size_t gm = m0 + wm * WM + i * 16 + 4 * lq + r;
                float v = acc[i][j][r] + bv;
                if constexpr (ACT == 1) v = gelu_tanh(v);
                size_t o = gm * (size_t)N + gn;
                if constexpr (RES == 2) v += ((const float*)res)[o];
                if constexpr (RES == 3) v += f32f ? ((const float*)res)[o] : (float)((const bf16*)res)[o];
                if constexpr (OUTM == 0) ((bf16*)out0)[o] = bf16(v);
                else if constexpr (OUTM == 1) ((float*)out0)[o] = v;
                else if constexpr (OUTM == 2) { ((float*)out0)[o] = v; ((bf16*)out1)[o] = bf16(v); }
                else { if (f32f) ((float*)out0)[o] = v; else ((bf16*)out0)[o] = bf16(v); }
            }
        }
    }
}

#define GEMM_KERNEL(NAME, BM, BN, BK, WM, WN, BIAS, ACT, RES, OUTM, AMIX)                                   \
    __global__ __launch_bounds__(256) void NAME(const bf16* A, int lda, const bf16* BT, const bf16* bias,   \
                                                const void* res, void* out0, void* out1, int M, int N,      \
                                                int K, const int* flagp) {                                  \
        gemm_core<BM, BN, BK, WM, WN, BIAS, ACT, RES, OUTM, AMIX>(A, lda, BT, bias, res, out0, out1, M, N,  \
                                                                  K, flagp);                                \
    }

GEMM_KERNEL(g_down,   128, 64, 32, 64, 32, 0, 0, 0, 0, 1)   // mix @ [qu|ku|vu] -> tq (M x 192)
GEMM_KERNEL(g_up,     128, 128, 32, 64, 64, 0, 0, 0, 0, 0)  // tq slice @ {qv,kv,vv}T -> q/k/v
GEMM_KERNEL(g_attn,   128, 128, 32, 64, 64, 1, 0, 3, 1, 0)  // ys @ out_w + out_b + x -> x1f (f32)
GEMM_KERNEL(g_ffn1,   128, 128, 32, 64, 64, 1, 1, 0, 0, 0)  // gelu(h2 @ w1 + b1) -> mid
GEMM_KERNEL(g_ffn2,   128, 128, 32, 64, 64, 1, 0, 2, 2, 0)  // mid @ w2 + b2 + x1f -> x1f, x2b
GEMM_KERNEL(g_addown, 64, 32, 32, 32, 16, 1, 1, 0, 0, 0)    // gelu(x2 @ ad_w + ad_b) -> adt
GEMM_KERNEL(g_adup,   128, 128, 32, 64, 64, 1, 0, 2, 3, 0)  // adt @ au_w + au_b + x1f -> d_out

// ---------------- host side ----------------
extern "C" void kernel_launch(void* const* d_in, const int* in_sizes, int n_in,
                              void* d_out, int out_size, void* d_ws, size_t ws_size,
                              hipStream_t stream) {
    (void)in_sizes; (void)n_in; (void)out_size;
    const void* x     = d_in[0];
    const void* h0    = d_in[1];
    const void* ln1_g = d_in[2];
    const void* ln1_b = d_in[3];
    const void* tm_g  = d_in[4];
    const void* tm_b  = d_in[5];
    const void* qu    = d_in[6];
    const void* qv    = d_in[7];
    const void* ku    = d_in[8];
    const void* kv    = d_in[9];
    const void* vu    = d_in[10];
    const void* vv    = d_in[11];
    const void* td    = d_in[12];
    const void* out_w = d_in[13];
    const void* out_b = d_in[14];
    const void* ln2_g = d_in[15];
    const void* ln2_b = d_in[16];
    const void* ffn_w1 = d_in[17];
    const void* ffn_b1 = d_in[18];
    const void* ffn_w2 = d_in[19];
    const void* ffn_b2 = d_in[20];
    const void* ad_w  = d_in[21];
    const void* ad_b  = d_in[22];
    const void* au_w  = d_in[23];
    const void* au_b  = d_in[24];

    char* ws = (char*)d_ws;
    size_t off = 0;
    auto alloc = [&](size_t bytes) -> void* {
        void* p = ws + off;
        off += (bytes + 255) & ~(size_t)255;
        return p;
    };
    const size_t BTC = (size_t)B_ * T_ * C_;
    bf16* uT  = (bf16*)alloc((size_t)192 * C_ * 2);   // [quT;kuT;vuT] rows 0-191
    bf16* qvT = (bf16*)alloc((size_t)C_ * R_ * 2);
    bf16* kvT = (bf16*)alloc((size_t)C_ * R_ * 2);
    bf16* vvT = (bf16*)alloc((size_t)C_ * R_ * 2);
    bf16* owT = (bf16*)alloc((size_t)C_ * C_ * 2);
    bf16* w1T = (bf16*)alloc((size_t)C_ * FF_ * 2);
    bf16* w2T = (bf16*)alloc((size_t)C_ * FF_ * 2);
    bf16* adT = (bf16*)alloc((size_t)C_ * AR_ * 2);
    bf16* auT = (bf16*)alloc((size_t)C_ * AR_ * 2);
    bf16* c_ln1g = (bf16*)alloc(C_ * 2);
    bf16* c_ln1b = (bf16*)alloc(C_ * 2);
    bf16* c_tmg  = (bf16*)alloc(C_ * 2);
    bf16* c_tmb  = (bf16*)alloc(C_ * 2);
    bf16* c_td   = (bf16*)alloc(C_ * 2);
    bf16* c_outb = (bf16*)alloc(C_ * 2);
    bf16* c_ln2g = (bf16*)alloc(C_ * 2);
    bf16* c_ln2b = (bf16*)alloc(C_ * 2);
    bf16* c_fb1  = (bf16*)alloc(FF_ * 2);
    bf16* c_fb2  = (bf16*)alloc(C_ * 2);
    bf16* c_adb  = (bf16*)alloc(AR_ * 2);
    bf16* c_aub  = (bf16*)alloc(C_ * 2);
    bf16* c_h0   = (bf16*)alloc((size_t)B_ * C_ * 2);
    int*  flag   = (int*)alloc(256);
    // xn and vb contiguous: x1f (f32, 64MB) aliases both once dead
    bf16* xn = (bf16*)alloc(BTC * 2);
    bf16* vb = (bf16*)alloc(BTC * 2);
    bf16* qb = (bf16*)alloc(BTC * 2);   // q -> ys -> (small path) ffn mid
    bf16* kb = (bf16*)alloc(BTC * 2);   // k -> h2n -> x2b
    bf16* tq = (bf16*)alloc((size_t)M_ * 192 * 2);  // fused low-rank out; reused adapter mid
    float* carry = (float*)alloc((size_t)B_ * NC_ * C_ * 4);
    float* hin   = (float*)alloc((size_t)B_ * NC_ * C_ * 4);
    float* x1f = (float*)xn;

    const size_t midb_bytes = (size_t)M_ * FF_ * 2;
    bool big = ws_size >= off + midb_bytes + (1u << 20);
    bf16* midb = big ? (bf16*)alloc(midb_bytes) : qb;
    const int nchunk = big ? 1 : 4;
    const int crows = M_ / nchunk;

    detect_kernel<<<1, 256, 0, stream>>>((const u32*)x, flag);

    // ---- one prep kernel: 11 transposes + 13 vec converts ----
    PrepArgs pa;
    const void* tsrc[11] = {qu, ku, vu, qv, kv, vv, out_w, ffn_w1, ffn_w2, ad_w, au_w};
    void* tdst[11] = {uT, uT + (size_t)64 * C_, uT + (size_t)128 * C_, qvT, kvT, vvT, owT, w1T, w2T, adT, auT};
    int tK[11] = {C_, C_, C_, R_, R_, R_, C_, C_, FF_, C_, AR_};
    int tN[11] = {R_, R_, R_, C_, C_, C_, C_, FF_, C_, AR_, C_};
    const void* vsrc[13] = {ln1_g, ln1_b, tm_g, tm_b, td, out_b, ln2_g, ln2_b, ffn_b1, ffn_b2, ad_b, au_b, h0};
    void* vdst[13] = {c_ln1g, c_ln1b, c_tmg, c_tmb, c_td, c_outb, c_ln2g, c_ln2b, c_fb1, c_fb2, c_adb, c_aub, c_h0};
    int vn[13] = {C_, C_, C_, C_, C_, C_, C_, C_, FF_, C_, AR_, C_, B_ * C_};
    int nb = 0;
    for (int i = 0; i < 11; ++i) {
        pa.src[i] = tsrc[i]; pa.dst[i] = tdst[i]; pa.K[i] = tK[i]; pa.N[i] = tN[i];
        pa.start[i] = nb;
        nb += ((tN[i] + 31) / 32) * ((tK[i] + 31) / 32);
    }
    for (int i = 0; i < 13; ++i) {
        pa.src[11 + i] = vsrc[i]; pa.dst[11 + i] = vdst[i]; pa.K[11 + i] = 0; pa.N[11 + i] = vn[i];
        pa.start[11 + i] = nb;
        nb += 1;
    }
    pa.start[24] = nb;
    pa.start[25] = nb;
    pa.n_tr = 11;
    weight_prep<<<nb, 256, 0, stream>>>(pa, flag);

    ln2x_kernel<<<M_, 256, 0, stream>>>(x, flag, c_ln1g, c_ln1b, c_tmg, c_tmb, xn);

    // fused down-projection (token-shift mix folded into A staging): tq = mix @ [qu|ku|vu]
    g_down<<<dim3(M_ / 128, 3), 256, 0, stream>>>(xn, C_, uT, nullptr, nullptr, tq, nullptr, M_, 192, C_, flag);
    // up-projections (A = strided slice of tq)
    g_up<<<dim3(M_ / 128, C_ / 128), 256, 0, stream>>>(tq + 0,   192, qvT, nullptr, nullptr, qb, nullptr, M_, C_, R_, flag);
    g_up<<<dim3(M_ / 128, C_ / 128), 256, 0, stream>>>(tq + 64,  192, kvT, nullptr, nullptr, kb, nullptr, M_, C_, R_, flag);
    g_up<<<dim3(M_ / 128, C_ / 128), 256, 0, stream>>>(tq + 128, 192, vvT, nullptr, nullptr, vb, nullptr, M_, C_, R_, flag);

    scan_pass1<<<B_ * NC_ * (C_ / 256), 256, 0, stream>>>(kb, vb, c_td, carry);
    scan_combine<<<B_ * (C_ / 256), 256, 0, stream>>>(carry, hin, c_h0, c_td, d_out, flag);
    scan_pass2<<<B_ * NC_ * (C_ / 256), 256, 0, stream>>>(qb, kb, vb, c_td, hin);

    // attn out projection + residual(x) -> x1f (f32; aliases xn+vb)
    g_attn<<<dim3(M_ / 128, C_ / 128), 256, 0, stream>>>(qb, C_, owT, c_outb, x, x1f, nullptr, M_, C_, C_, flag);

    ln_single_kernel<<<M_, 256, 0, stream>>>(x1f, c_ln2g, c_ln2b, kb);
    for (int c = 0; c < nchunk; ++c) {
        bf16* h2c = kb + (size_t)c * crows * C_;
        bf16* mid = big ? midb + (size_t)c * crows * FF_ : midb;
        float* x1c = x1f + (size_t)c * crows * C_;
        g_ffn1<<<dim3(crows / 128, FF_ / 128), 256, 0, stream>>>(h2c, C_, w1T, c_fb1, nullptr, mid, nullptr, crows, FF_, C_, flag);
        g_ffn2<<<dim3(crows / 128, C_ / 128), 256, 0, stream>>>(mid, FF_, w2T, c_fb2, x1c, x1c, h2c, crows, C_, FF_, flag);
    }

    g_addown<<<dim3(M_ / 64, 1), 256, 0, stream>>>(kb, C_, adT, c_adb, nullptr, tq, nullptr, M_, AR_, C_, flag);
    g_adup<<<dim3(M_ / 128, C_ / 128), 256, 0, stream>>>(tq, AR_, auT, c_aub, x1f, d_out, nullptr, M_, C_, AR_, flag);
}

// Round 4
// 1804.991 us; speedup vs baseline: 1.0577x; 1.0172x over previous
//
#include <hip/hip_runtime.h>
#include <hip/hip_bf16.h>

typedef __bf16 bf16x8 __attribute__((ext_vector_type(8)));
typedef float  f32x4  __attribute__((ext_vector_type(4)));
typedef __hip_bfloat16 bf16;
typedef unsigned short u16;
typedef unsigned int   u32;

static constexpr int B_ = 8, T_ = 2048, C_ = 1024, R_ = 64, AR_ = 32, FF_ = 4096;
static constexpr int M_ = B_ * T_;
static constexpr int NC_ = 64;
static constexpr int L_ = T_ / NC_;

__device__ __forceinline__ float gelu_tanh(float x) {
    float x3 = x * x * x;
    return 0.5f * x * (1.0f + tanhf(0.7978845608028654f * (x + 0.044715f * x3)));
}
__device__ __forceinline__ float dual1(const void* p, size_t i, int f) {
    return f ? ((const float*)p)[i] : (float)((const bf16*)p)[i];
}

// aligned vector copy (BYTES in {8,16,32,64}); pointers must be 8/16B aligned as used
template <int BYTES>
__device__ __forceinline__ void vcopy(void* d, const void* s) {
#pragma unroll
    for (int i = 0; i < BYTES / 16; ++i) ((uint4*)d)[i] = ((const uint4*)s)[i];
    if constexpr (BYTES % 16 == 8)
        *(uint2*)((char*)d + (BYTES / 16) * 16) = *(const uint2*)((const char*)s + (BYTES / 16) * 16);
}

// ---------------- dtype detector ----------------
__global__ __launch_bounds__(256) void detect_kernel(const u32* __restrict__ x, int* __restrict__ flag) {
    __shared__ int cnt;
    if (threadIdx.x == 0) cnt = 0;
    __syncthreads();
    u32 u = x[threadIdx.x];
    int e = (u >> 7) & 0xFF;
    int vote = (e >= 113 && e <= 130) ? 1 : 0;
#pragma unroll
    for (int o = 32; o; o >>= 1) vote += __shfl_down(vote, o);
    if ((threadIdx.x & 63) == 0) atomicAdd(&cnt, vote);
    __syncthreads();
    if (threadIdx.x == 0) flag[0] = (cnt >= 128) ? 0 : 1;
}

// ---------------- weight prep: transposes + vec converts ----------------
struct PrepArgs {
    const void* src[24];
    void* dst[24];
    int K[24], N[24];
    int start[26];
    int n_tr;
};
__global__ __launch_bounds__(256) void weight_prep(PrepArgs a, const int* __restrict__ flagp) {
    __shared__ float tile[32][33];
    int f = flagp[0];
    int bid = blockIdx.x;
    int t = 0;
    while (bid >= a.start[t + 1]) ++t;
    int local = bid - a.start[t];
    if (t < a.n_tr) {
        int K = a.K[t], N = a.N[t];
        int nbx = (N + 31) >> 5;
        int bx = local % nbx, by = local / nbx;
        int n0 = bx * 32, k0 = by * 32;
        int tx = threadIdx.x & 31, ty = threadIdx.x >> 5;
        const void* in = a.src[t];
        bf16* out = (bf16*)a.dst[t];
#pragma unroll
        for (int j = 0; j < 4; ++j) {
            int k = k0 + ty + j * 8, n = n0 + tx;
            if (k < K && n < N) tile[ty + j * 8][tx] = dual1(in, (size_t)k * N + n, f);
        }
        __syncthreads();
#pragma unroll
        for (int j = 0; j < 4; ++j) {
            int n = n0 + ty + j * 8, k = k0 + tx;
            if (n < N && k < K) out[(size_t)n * K + k] = bf16(tile[tx][ty + j * 8]);
        }
    } else {
        const void* s = a.src[t];
        bf16* d = (bf16*)a.dst[t];
        for (int i = threadIdx.x; i < a.N[t]; i += 256) d[i] = bf16(dual1(s, i, f));
    }
}

// ---------------- block reduction ----------------
__device__ __forceinline__ float2 block_sum2(float a, float b, float2* rbuf, int tid) {
#pragma unroll
    for (int o = 32; o; o >>= 1) { a += __shfl_down(a, o); b += __shfl_down(b, o); }
    if ((tid & 63) == 0) rbuf[tid >> 6] = make_float2(a, b);
    __syncthreads();
    float2 r = make_float2(rbuf[0].x + rbuf[1].x + rbuf[2].x + rbuf[3].x,
                           rbuf[0].y + rbuf[1].y + rbuf[2].y + rbuf[3].y);
    __syncthreads();
    return r;
}

// ---------------- double layernorm -> xn ----------------
__global__ __launch_bounds__(256) void ln2x_kernel(const void* __restrict__ x, const int* __restrict__ flagp,
                                                   const bf16* __restrict__ g1, const bf16* __restrict__ b1,
                                                   const bf16* __restrict__ g2, const bf16* __restrict__ b2,
                                                   bf16* __restrict__ xn) {
    __shared__ float2 rbuf[4];
    int row = blockIdx.x, tid = threadIdx.x;
    int f = flagp[0];
    float v[4];
#pragma unroll
    for (int j = 0; j < 4; ++j) v[j] = dual1(x, (size_t)row * C_ + tid + j * 256, f);
    float s = 0.f, s2 = 0.f;
#pragma unroll
    for (int j = 0; j < 4; ++j) { s += v[j]; s2 += v[j] * v[j]; }
    float2 st = block_sum2(s, s2, rbuf, tid);
    float mu = st.x * (1.0f / C_), var = st.y * (1.0f / C_) - mu * mu, rs = rsqrtf(var + 1e-5f);
#pragma unroll
    for (int j = 0; j < 4; ++j) {
        int c = tid + j * 256;
        v[j] = (v[j] - mu) * rs * (float)g1[c] + (float)b1[c];
    }
    s = 0.f; s2 = 0.f;
#pragma unroll
    for (int j = 0; j < 4; ++j) { s += v[j]; s2 += v[j] * v[j]; }
    st = block_sum2(s, s2, rbuf, tid);
    mu = st.x * (1.0f / C_); var = st.y * (1.0f / C_) - mu * mu; rs = rsqrtf(var + 1e-5f);
#pragma unroll
    for (int j = 0; j < 4; ++j) {
        int c = tid + j * 256;
        xn[(size_t)row * C_ + c] = bf16((v[j] - mu) * rs * (float)g2[c] + (float)b2[c]);
    }
}

// ---------------- single layernorm (f32 in, bf16 out) ----------------
__global__ __launch_bounds__(256) void ln_single_kernel(const float* __restrict__ x,
                                                        const bf16* __restrict__ g, const bf16* __restrict__ b,
                                                        bf16* __restrict__ out) {
    __shared__ float2 rbuf[4];
    int row = blockIdx.x, tid = threadIdx.x;
    float v[4];
#pragma unroll
    for (int j = 0; j < 4; ++j) v[j] = x[(size_t)row * C_ + tid + j * 256];
    float s = 0.f, s2 = 0.f;
#pragma unroll
    for (int j = 0; j < 4; ++j) { s += v[j]; s2 += v[j] * v[j]; }
    float2 st = block_sum2(s, s2, rbuf, tid);
    float mu = st.x * (1.0f / C_), var = st.y * (1.0f / C_) - mu * mu, rs = rsqrtf(var + 1e-5f);
#pragma unroll
    for (int j = 0; j < 4; ++j) {
        int c = tid + j * 256;
        out[(size_t)row * C_ + c] = bf16((v[j] - mu) * rs * (float)g[c] + (float)b[c]);
    }
}

// ---------------- chunked linear recurrence ----------------
__global__ __launch_bounds__(256) void scan_pass1(const bf16* __restrict__ kb, const bf16* __restrict__ vb,
                                                  const bf16* __restrict__ td, float* __restrict__ carry) {
    int cb = blockIdx.x & 3;
    int chunk = (blockIdx.x >> 2) & (NC_ - 1);
    int b = blockIdx.x >> 8;
    int c = cb * 256 + threadIdx.x;
    float d = expf(-expf((float)td[c]));
    float h = 0.f;
    size_t base = ((size_t)b * T_ + (size_t)chunk * L_) * C_ + c;
#pragma unroll 4
    for (int j = 0; j < L_; ++j) {
        float kk = (float)kb[base + (size_t)j * C_];
        float vv = (float)vb[base + (size_t)j * C_];
        h = d * h + kk * vv;
    }
    carry[((size_t)(b * NC_ + chunk)) * C_ + c] = h;
}

__global__ __launch_bounds__(256) void scan_combine(const float* __restrict__ carry, float* __restrict__ hin,
                                                    const bf16* __restrict__ h0b, const bf16* __restrict__ td,
                                                    void* __restrict__ dout, const int* __restrict__ flagp) {
    int f = flagp[0];
    int cb = blockIdx.x & 3;
    int b = blockIdx.x >> 2;
    int c = cb * 256 + threadIdx.x;
    float d = expf(-expf((float)td[c]));
    float dL = powf(d, (float)L_);
    float run = (float)h0b[(size_t)b * C_ + c];
    for (int i = 0; i < NC_; ++i) {
        size_t o = ((size_t)(b * NC_ + i)) * C_ + c;
        hin[o] = run;
        run = dL * run + carry[o];
    }
    size_t oo = (size_t)B_ * T_ * C_ + (size_t)b * C_ + c;
    if (f) ((float*)dout)[oo] = run; else ((bf16*)dout)[oo] = bf16(run);
}

__global__ __launch_bounds__(256) void scan_pass2(bf16* __restrict__ qb, const bf16* __restrict__ kb,
                                                  const bf16* __restrict__ vb, const bf16* __restrict__ td,
                                                  const float* __restrict__ hin) {
    int cb = blockIdx.x & 3;
    int chunk = (blockIdx.x >> 2) & (NC_ - 1);
    int b = blockIdx.x >> 8;
    int c = cb * 256 + threadIdx.x;
    float d = expf(-expf((float)td[c]));
    float h = hin[((size_t)(b * NC_ + chunk)) * C_ + c];
    size_t base = ((size_t)b * T_ + (size_t)chunk * L_) * C_ + c;
#pragma unroll 4
    for (int j = 0; j < L_; ++j) {
        size_t o = base + (size_t)j * C_;
        float kk = (float)kb[o], vv = (float)vb[o], qq = (float)qb[o];
        h = d * h + kk * vv;
        float sg = 1.0f / (1.0f + expf(-qq));
        qb[o] = bf16(sg * h);
    }
}

// ---------------- bf16 MFMA GEMM core with LDS-transposed vector epilogue ----------------
// RES: 0 none, 2 f32, 3 dual(flag). OUTM: 0 bf16, 1 f32, 2 f32 out0 + bf16 out1,
// 3 dual(flag) d_out, 4 three bf16 planes (width 1024) via out0/out1/out2.
template <int BM, int BN, int BK, int WM, int WN, int BIAS, int ACT, int RES, int OUTM, int AMIX>
__device__ __forceinline__ void gemm_core(const bf16* __restrict__ A, int lda, const bf16* __restrict__ BT,
                                          const bf16* __restrict__ bias, const void* __restrict__ res,
                                          void* __restrict__ out0, void* __restrict__ out1, void* __restrict__ out2,
                                          int M, int N, int K, const int* __restrict__ flagp) {
    constexpr int LDA = BK + 8;
    constexpr int WGM = BM / WM;
    constexpr int MT = WM / 16, NT = WN / 16;
    constexpr int KC = BK / 8;
    constexpr int CHA = BM * KC, CHB = BN * KC;
    constexpr int RA = (CHA + 255) / 256, RB = (CHB + 255) / 256;
    constexpr int CW = WN / 4;           // contiguous f32 per lane after LDS transpose
    constexpr int CHK = (CW >= 8) ? 8 : CW;
    constexpr int EPS = WN + 4;          // f32 row stride, (EPS*4)%16==0
    constexpr int SM_STAGE = (BM + BN) * LDA * 2;
    constexpr int SM_EPI = 4 * 16 * EPS * 4;
    constexpr int SM = (SM_STAGE > SM_EPI) ? SM_STAGE : SM_EPI;
    static_assert(WGM * (BN / WN) == 4, "4 waves");
    __shared__ char smem[SM];
    u16* sA = (u16*)smem;
    u16* sB = sA + BM * LDA;
    const int tid = threadIdx.x, lane = tid & 63, wid = tid >> 6;
    const int wm = wid % WGM, wn = wid / WGM;
    const int l15 = lane & 15, lq = lane >> 4;
    const size_t m0 = (size_t)blockIdx.x * BM, n0 = (size_t)blockIdx.y * BN;
    const int KT = K / BK;
    const int f32f = (RES == 3 || OUTM == 3) ? flagp[0] : 0;

    uint4 ra[RA], rb[RB];
    auto gload = [&](int kt) {
#pragma unroll
        for (int i = 0; i < RA; ++i) {
            int ci = tid + i * 256;
            if ((CHA % 256 == 0) || ci < CHA) {
                int r = ci / KC, kc = ci % KC;
                const u16* gp = (const u16*)A + (m0 + r) * (size_t)lda + (size_t)kt * BK + kc * 8;
                if constexpr (AMIX) {
                    uint4 c0 = *(const uint4*)gp;
                    uint4 p0 = make_uint4(0, 0, 0, 0);
                    if ((int)((m0 + r) % T_) != 0) p0 = *(const uint4*)(gp - lda);
                    bf16 cc[8], pp[8], oo[8];
                    *(uint4*)cc = c0; *(uint4*)pp = p0;
#pragma unroll
                    for (int j = 0; j < 8; ++j) oo[j] = bf16(0.5f * ((float)cc[j] + (float)pp[j]));
                    ra[i] = *(uint4*)oo;
                } else {
                    ra[i] = *(const uint4*)gp;
                }
            }
        }
#pragma unroll
        for (int i = 0; i < RB; ++i) {
            int ci = tid + i * 256;
            if ((CHB % 256 == 0) || ci < CHB) {
                int r = ci / KC, kc = ci % KC;
                rb[i] = *(const uint4*)((const u16*)BT + (n0 + r) * (size_t)K + (size_t)kt * BK + kc * 8);
            }
        }
    };
    auto lstore = [&]() {
#pragma unroll
        for (int i = 0; i < RA; ++i) {
            int ci = tid + i * 256;
            if ((CHA % 256 == 0) || ci < CHA) {
                int r = ci / KC, kc = ci % KC;
                *(uint4*)&sA[r * LDA + kc * 8] = ra[i];
            }
        }
#pragma unroll
        for (int i = 0; i < RB; ++i) {
            int ci = tid + i * 256;
            if ((CHB % 256 == 0) || ci < CHB) {
                int r = ci / KC, kc = ci % KC;
                *(uint4*)&sB[r * LDA + kc * 8] = rb[i];
            }
        }
    };

    f32x4 acc[MT][NT];
#pragma unroll
    for (int i = 0; i < MT; ++i)
#pragma unroll
        for (int j = 0; j < NT; ++j) acc[i][j] = 0.0f;

    gload(0);
    for (int kt = 0; kt < KT; ++kt) {
        __syncthreads();
        lstore();
        if (kt + 1 < KT) gload(kt + 1);
        __syncthreads();
        bf16x8 af[MT], bfr[NT];
#pragma unroll
        for (int i = 0; i < MT; ++i)
            af[i] = *(const bf16x8*)&sA[(wm * WM + i * 16 + l15) * LDA + 8 * lq];
#pragma unroll
        for (int j = 0; j < NT; ++j)
            bfr[j] = *(const bf16x8*)&sB[(wn * WN + j * 16 + l15) * LDA + 8 * lq];
#pragma unroll
        for (int i = 0; i < MT; ++i)
#pragma unroll
            for (int j = 0; j < NT; ++j)
                acc[i][j] = __builtin_amdgcn_mfma_f32_16x16x32_bf16(af[i], bfr[j], acc[i][j], 0, 0, 0);
    }

    // ---- LDS-transposed epilogue: each lane ends with CW contiguous f32 ----
    __syncthreads();                       // staging LDS is being repurposed
    float* ep = (float*)smem + (size_t)wid * 16 * EPS;   // wave-private 16 x EPS region
    const int rrow = lane >> 2, seg = lane & 3;
    const size_t colbase = n0 + (size_t)wn * WN + (size_t)seg * CW;
    // plane select (OUTM 4): BN=128 tiles never straddle 1024-wide planes
    bf16* planep = nullptr;
    size_t colp = 0;
    if constexpr (OUTM == 4) {
        int plane = (int)(n0 >> 10);
        bf16* pls[3] = {(bf16*)out0, (bf16*)out1, (bf16*)out2};
        planep = pls[plane];
        colp = colbase - ((size_t)plane << 10);
    }
#pragma unroll
    for (int i = 0; i < MT; ++i) {
        // scatter acc slab into wave-private LDS (2-way conflicts max)
#pragma unroll
        for (int j = 0; j < NT; ++j)
#pragma unroll
            for (int r = 0; r < 4; ++r)
                ep[(4 * lq + r) * EPS + j * 16 + l15] = acc[i][j][r];
        // wave-internal ds ordering: compiler inserts lgkmcnt waits; no barrier needed
        const size_t gm = m0 + (size_t)wm * WM + i * 16 + rrow;
        const size_t gidx = gm * (size_t)N + colbase;
#pragma unroll
        for (int c0 = 0; c0 < CW; c0 += CHK) {
            alignas(16) float v[CHK];
            vcopy<CHK * 4>(v, ep + rrow * EPS + seg * CW + c0);
            if constexpr (BIAS) {
                alignas(16) bf16 bt[CHK];
                vcopy<CHK * 2>(bt, bias + colbase + c0);
#pragma unroll
                for (int t = 0; t < CHK; ++t) v[t] += (float)bt[t];
            }
            if constexpr (ACT == 1) {
#pragma unroll
                for (int t = 0; t < CHK; ++t) v[t] = gelu_tanh(v[t]);
            }
            if constexpr (RES == 2) {
                alignas(16) float rv[CHK];
                vcopy<CHK * 4>(rv, (const float*)res + gidx + c0);
#pragma unroll
                for (int t = 0; t < CHK; ++t) v[t] += rv[t];
            }
            if constexpr (RES == 3) {
                if (f32f) {
                    alignas(16) float rv[CHK];
                    vcopy<CHK * 4>(rv, (const float*)res + gidx + c0);
#pragma unroll
                    for (int t = 0; t < CHK; ++t) v[t] += rv[t];
                } else {
                    alignas(16) bf16 rv[CHK];
                    vcopy<CHK * 2>(rv, (const bf16*)res + gidx + c0);
#pragma unroll
                    for (int t = 0; t < CHK; ++t) v[t] += (float)rv[t];
                }
            }
            if constexpr (OUTM == 0 || OUTM == 2 || OUTM == 4) {
                alignas(16) bf16 ob[CHK];
#pragma unroll
                for (int t = 0; t < CHK; ++t) ob[t] = bf16(v[t]);
                if constexpr (OUTM == 0) vcopy<CHK * 2>((bf16*)out0 + gidx + c0, ob);
                if constexpr (OUTM == 2) {
                    vcopy<CHK * 4>((float*)out0 + gidx + c0, v);
                    vcopy<CHK * 2>((bf16*)out1 + gidx + c0, ob);
                }
                if constexpr (OUTM == 4) vcopy<CHK * 2>(planep + (gm << 10) + colp + c0, ob);
            }
            if constexpr (OUTM == 1) vcopy<CHK * 4>((float*)out0 + gidx + c0, v);
            if constexpr (OUTM == 3) {
                if (f32f) {
                    vcopy<CHK * 4>((float*)out0 + gidx + c0, v);
                } else {
                    alignas(16) bf16 ob[CHK];
#pragma unroll
                    for (int t = 0; t < CHK; ++t) ob[t] = bf16(v[t]);
                    vcopy<CHK * 2>((bf16*)out0 + gidx + c0, ob);
                }
            }
        }
    }
}

#define GEMM_KERNEL(NAME, BM, BN, BK, WM, WN, BIAS, ACT, RES, OUTM, AMIX)                                     \
    __global__ __launch_bounds__(256) void NAME(const bf16* A, int lda, const bf16* BT, const bf16* bias,     \
                                                const void* res, void* out0, void* out1, void* out2, int M,   \
                                                int N, int K, const int* flagp) {                             \
        gemm_core<BM, BN, BK, WM, WN, BIAS, ACT, RES, OUTM, AMIX>(A, lda, BT, bias, res, out0, out1, out2,    \
                                                                  M, N, K, flagp);                            \
    }

GEMM_KERNEL(g_down,   128, 64, 32, 64, 32, 0, 0, 0, 0, 1)   // mix @ [qu|ku|vu] -> tq (M x 192)
GEMM_KERNEL(g_attn,   128, 128, 32, 64, 64, 1, 0, 3, 1, 0)  // ys @ out_w + out_b + x -> x1f
GEMM_KERNEL(g_ffn1,   128, 128, 32, 64, 64, 1, 1, 0, 0, 0)  // gelu(h2 @ w1 + b1) -> mid
GEMM_KERNEL(g_ffn2,   128, 128, 32, 64, 64, 1, 0, 2, 2, 0)  // mid @ w2 + b2 + x1f -> x1f, x2b
GEMM_KERNEL(g_addown, 64, 32, 32, 32, 16, 1, 1, 0, 0, 0)    // gelu(x2 @ ad_w + ad_b) -> adt
GEMM_KERNEL(g_adup,   128, 128, 32, 64, 64, 1, 0, 2, 3, 0)  // adt @ au_w + au_b + x1f -> d_out

// fused up-projection: block-diagonal A (plane p uses tq cols [64p,64p+64)), B = [qvT;kvT;vvT]
__global__ __launch_bounds__(256) void g_upf(const bf16* A, int lda, const bf16* BT, const bf16* bias,
                                             const void* res, void* out0, void* out1, void* out2, int M,
                                             int N, int K, const int* flagp) {
    const bf16* Ap = A + (size_t)(blockIdx.y >> 3) * 64;
    gemm_core<128, 128, 32, 64, 64, 0, 0, 0, 4, 0>(Ap, lda, BT, bias, res, out0, out1, out2, M, N, K, flagp);
}

// ---------------- host side ----------------
extern "C" void kernel_launch(void* const* d_in, const int* in_sizes, int n_in,
                              void* d_out, int out_size, void* d_ws, size_t ws_size,
                              hipStream_t stream) {
    (void)in_sizes; (void)n_in; (void)out_size;
    const void* x     = d_in[0];
    const void* h0    = d_in[1];
    const void* ln1_g = d_in[2];
    const void* ln1_b = d_in[3];
    const void* tm_g  = d_in[4];
    const void* tm_b  = d_in[5];
    const void* qu    = d_in[6];
    const void* qv    = d_in[7];
    const void* ku    = d_in[8];
    const void* kv    = d_in[9];
    const void* vu    = d_in[10];
    const void* vv    = d_in[11];
    const void* td    = d_in[12];
    const void* out_w = d_in[13];
    const void* out_b = d_in[14];
    const void* ln2_g = d_in[15];
    const void* ln2_b = d_in[16];
    const void* ffn_w1 = d_in[17];
    const void* ffn_b1 = d_in[18];
    const void* ffn_w2 = d_in[19];
    const void* ffn_b2 = d_in[20];
    const void* ad_w  = d_in[21];
    const void* ad_b  = d_in[22];
    const void* au_w  = d_in[23];
    const void* au_b  = d_in[24];

    char* ws = (char*)d_ws;
    size_t off = 0;
    auto alloc = [&](size_t bytes) -> void* {
        void* p = ws + off;
        off += (bytes + 255) & ~(size_t)255;
        return p;
    };
    const size_t BTC = (size_t)B_ * T_ * C_;
    bf16* uT  = (bf16*)alloc((size_t)192 * C_ * 2);    // [quT;kuT;vuT]
    bf16* vT3 = (bf16*)alloc((size_t)3072 * R_ * 2);   // [qvT;kvT;vvT]
    bf16* owT = (bf16*)alloc((size_t)C_ * C_ * 2);
    bf16* w1T = (bf16*)alloc((size_t)C_ * FF_ * 2);
    bf16* w2T = (bf16*)alloc((size_t)C_ * FF_ * 2);
    bf16* adT = (bf16*)alloc((size_t)C_ * AR_ * 2);
    bf16* auT = (bf16*)alloc((size_t)C_ * AR_ * 2);
    bf16* c_ln1g = (bf16*)alloc(C_ * 2);
    bf16* c_ln1b = (bf16*)alloc(C_ * 2);
    bf16* c_tmg  = (bf16*)alloc(C_ * 2);
    bf16* c_tmb  = (bf16*)alloc(C_ * 2);
    bf16* c_td   = (bf16*)alloc(C_ * 2);
    bf16* c_outb = (bf16*)alloc(C_ * 2);
    bf16* c_ln2g = (bf16*)alloc(C_ * 2);
    bf16* c_ln2b = (bf16*)alloc(C_ * 2);
    bf16* c_fb1  = (bf16*)alloc(FF_ * 2);
    bf16* c_fb2  = (bf16*)alloc(C_ * 2);
    bf16* c_adb  = (bf16*)alloc(AR_ * 2);
    bf16* c_aub  = (bf16*)alloc(C_ * 2);
    bf16* c_h0   = (bf16*)alloc((size_t)B_ * C_ * 2);
    int*  flag   = (int*)alloc(256);
    bf16* xn = (bf16*)alloc(BTC * 2);
    bf16* vb = (bf16*)alloc(BTC * 2);
    bf16* qb = (bf16*)alloc(BTC * 2);
    bf16* kb = (bf16*)alloc(BTC * 2);
    bf16* tq = (bf16*)alloc((size_t)M_ * 192 * 2);
    float* carry = (float*)alloc((size_t)B_ * NC_ * C_ * 4);
    float* hin   = (float*)alloc((size_t)B_ * NC_ * C_ * 4);
    float* x1f = (float*)xn;   // aliases xn+vb (dead by then)

    const size_t midb_bytes = (size_t)M_ * FF_ * 2;
    bool big = ws_size >= off + midb_bytes + (1u << 20);
    bf16* midb = big ? (bf16*)alloc(midb_bytes) : qb;
    const int nchunk = big ? 1 : 4;
    const int crows = M_ / nchunk;

    detect_kernel<<<1, 256, 0, stream>>>((const u32*)x, flag);

    PrepArgs pa;
    const void* tsrc[11] = {qu, ku, vu, qv, kv, vv, out_w, ffn_w1, ffn_w2, ad_w, au_w};
    void* tdst[11] = {uT, uT + (size_t)64 * C_, uT + (size_t)128 * C_,
                      vT3, vT3 + (size_t)1024 * R_, vT3 + (size_t)2048 * R_, owT, w1T, w2T, adT, auT};
    int tK[11] = {C_, C_, C_, R_, R_, R_, C_, C_, FF_, C_, AR_};
    int tN[11] = {R_, R_, R_, C_, C_, C_, C_, FF_, C_, AR_, C_};
    const void* vsrc[13] = {ln1_g, ln1_b, tm_g, tm_b, td, out_b, ln2_g, ln2_b, ffn_b1, ffn_b2, ad_b, au_b, h0};
    void* vdst[13] = {c_ln1g, c_ln1b, c_tmg, c_tmb, c_td, c_outb, c_ln2g, c_ln2b, c_fb1, c_fb2, c_adb, c_aub, c_h0};
    int vn[13] = {C_, C_, C_, C_, C_, C_, C_, C_, FF_, C_, AR_, C_, B_ * C_};
    int nb = 0;
    for (int i = 0; i < 11; ++i) {
        pa.src[i] = tsrc[i]; pa.dst[i] = tdst[i]; pa.K[i] = tK[i]; pa.N[i] = tN[i];
        pa.start[i] = nb;
        nb += ((tN[i] + 31) / 32) * ((tK[i] + 31) / 32);
    }
    for (int i = 0; i < 13; ++i) {
        pa.src[11 + i] = vsrc[i]; pa.dst[11 + i] = vdst[i]; pa.K[11 + i] = 0; pa.N[11 + i] = vn[i];
        pa.start[11 + i] = nb;
        nb += 1;
    }
    pa.start[24] = nb;
    pa.start[25] = nb;
    pa.n_tr = 11;
    weight_prep<<<nb, 256, 0, stream>>>(pa, flag);

    ln2x_kernel<<<M_, 256, 0, stream>>>(x, flag, c_ln1g, c_ln1b, c_tmg, c_tmb, xn);

    g_down<<<dim3(M_ / 128, 3), 256, 0, stream>>>(xn, C_, uT, nullptr, nullptr, tq, nullptr, nullptr, M_, 192, C_, flag);
    g_upf<<<dim3(M_ / 128, 24), 256, 0, stream>>>(tq, 192, vT3, nullptr, nullptr, qb, kb, vb, M_, 3072, R_, flag);

    scan_pass1<<<B_ * NC_ * (C_ / 256), 256, 0, stream>>>(kb, vb, c_td, carry);
    scan_combine<<<B_ * (C_ / 256), 256, 0, stream>>>(carry, hin, c_h0, c_td, d_out, flag);
    scan_pass2<<<B_ * NC_ * (C_ / 256), 256, 0, stream>>>(qb, kb, vb, c_td, hin);

    g_attn<<<dim3(M_ / 128, C_ / 128), 256, 0, stream>>>(qb, C_, owT, c_outb, x, x1f, nullptr, nullptr, M_, C_, C_, flag);

    ln_single_kernel<<<M_, 256, 0, stream>>>(x1f, c_ln2g, c_ln2b, kb);
    for (int c = 0; c < nchunk; ++c) {
        bf16* h2c = kb + (size_t)c * crows * C_;
        bf16* mid = big ? midb + (size_t)c * crows * FF_ : midb;
        float* x1c = x1f + (size_t)c * crows * C_;
        g_ffn1<<<dim3(crows / 128, FF_ / 128), 256, 0, stream>>>(h2c, C_, w1T, c_fb1, nullptr, mid, nullptr, nullptr, crows, FF_, C_, flag);
        g_ffn2<<<dim3(crows / 128, C_ / 128), 256, 0, stream>>>(mid, FF_, w2T, c_fb2, x1c, x1c, h2c, nullptr, crows, C_, FF_, flag);
    }

    g_addown<<<dim3(M_ / 64, 1), 256, 0, stream>>>(kb, C_, adT, c_adb, nullptr, tq, nullptr, nullptr, M_, AR_, C_, flag);
    g_adup<<<dim3(M_ / 128, C_ / 128), 256, 0, stream>>>(tq, AR_, auT, c_aub, x1f, d_out, nullptr, nullptr, M_, C_, AR_, flag);
}

// Round 5
// 1067.938 us; speedup vs baseline: 1.7877x; 1.6902x over previous
//
#include <hip/hip_runtime.h>
#include <hip/hip_bf16.h>

typedef __bf16 bf16x8 __attribute__((ext_vector_type(8)));
typedef float  f32x4  __attribute__((ext_vector_type(4)));
typedef __hip_bfloat16 bf16;
typedef unsigned short u16;
typedef unsigned int   u32;

static constexpr int B_ = 8, T_ = 2048, C_ = 1024, R_ = 64, AR_ = 32, FF_ = 4096;
static constexpr int M_ = B_ * T_;
static constexpr int NC_ = 64;
static constexpr int L_ = T_ / NC_;

__device__ __forceinline__ float gelu_tanh(float x) {
    float x3 = x * x * x;
    return 0.5f * x * (1.0f + tanhf(0.7978845608028654f * (x + 0.044715f * x3)));
}
__device__ __forceinline__ float dual1(const void* p, size_t i, int f) {
    return f ? ((const float*)p)[i] : (float)((const bf16*)p)[i];
}
// async global -> LDS, 16B per lane (lane-ordered destination)
__device__ __forceinline__ void gld16(const void* g, void* l) {
    __builtin_amdgcn_global_load_lds((const __attribute__((address_space(1))) void*)g,
                                     (__attribute__((address_space(3))) void*)l, 16, 0, 0);
}

template <int BYTES>
__device__ __forceinline__ void vcopy(void* d, const void* s) {
#pragma unroll
    for (int i = 0; i < BYTES / 16; ++i) ((uint4*)d)[i] = ((const uint4*)s)[i];
    if constexpr (BYTES % 16 == 8)
        *(uint2*)((char*)d + (BYTES / 16) * 16) = *(const uint2*)((const char*)s + (BYTES / 16) * 16);
}

// ---------------- dtype detector ----------------
__global__ __launch_bounds__(256) void detect_kernel(const u32* __restrict__ x, int* __restrict__ flag) {
    __shared__ int cnt;
    if (threadIdx.x == 0) cnt = 0;
    __syncthreads();
    u32 u = x[threadIdx.x];
    int e = (u >> 7) & 0xFF;
    int vote = (e >= 113 && e <= 130) ? 1 : 0;
#pragma unroll
    for (int o = 32; o; o >>= 1) vote += __shfl_down(vote, o);
    if ((threadIdx.x & 63) == 0) atomicAdd(&cnt, vote);
    __syncthreads();
    if (threadIdx.x == 0) flag[0] = (cnt >= 128) ? 0 : 1;
}

// ---------------- weight prep ----------------
struct PrepArgs {
    const void* src[24];
    void* dst[24];
    int K[24], N[24];
    int start[26];
    int n_tr;
};
__global__ __launch_bounds__(256) void weight_prep(PrepArgs a, const int* __restrict__ flagp) {
    __shared__ float tile[32][33];
    int f = flagp[0];
    int bid = blockIdx.x;
    int t = 0;
    while (bid >= a.start[t + 1]) ++t;
    int local = bid - a.start[t];
    if (t < a.n_tr) {
        int K = a.K[t], N = a.N[t];
        int nbx = (N + 31) >> 5;
        int bx = local % nbx, by = local / nbx;
        int n0 = bx * 32, k0 = by * 32;
        int tx = threadIdx.x & 31, ty = threadIdx.x >> 5;
        const void* in = a.src[t];
        bf16* out = (bf16*)a.dst[t];
#pragma unroll
        for (int j = 0; j < 4; ++j) {
            int k = k0 + ty + j * 8, n = n0 + tx;
            if (k < K && n < N) tile[ty + j * 8][tx] = dual1(in, (size_t)k * N + n, f);
        }
        __syncthreads();
#pragma unroll
        for (int j = 0; j < 4; ++j) {
            int n = n0 + ty + j * 8, k = k0 + tx;
            if (n < N && k < K) out[(size_t)n * K + k] = bf16(tile[tx][ty + j * 8]);
        }
    } else {
        const void* s = a.src[t];
        bf16* d = (bf16*)a.dst[t];
        for (int i = threadIdx.x; i < a.N[t]; i += 256) d[i] = bf16(dual1(s, i, f));
    }
}

// ---------------- block reduction ----------------
__device__ __forceinline__ float2 block_sum2(float a, float b, float2* rbuf, int tid) {
#pragma unroll
    for (int o = 32; o; o >>= 1) { a += __shfl_down(a, o); b += __shfl_down(b, o); }
    if ((tid & 63) == 0) rbuf[tid >> 6] = make_float2(a, b);
    __syncthreads();
    float2 r = make_float2(rbuf[0].x + rbuf[1].x + rbuf[2].x + rbuf[3].x,
                           rbuf[0].y + rbuf[1].y + rbuf[2].y + rbuf[3].y);
    __syncthreads();
    return r;
}

// ---------------- double layernorm -> xn ----------------
__global__ __launch_bounds__(256) void ln2x_kernel(const void* __restrict__ x, const int* __restrict__ flagp,
                                                   const bf16* __restrict__ g1, const bf16* __restrict__ b1,
                                                   const bf16* __restrict__ g2, const bf16* __restrict__ b2,
                                                   bf16* __restrict__ xn) {
    __shared__ float2 rbuf[4];
    int row = blockIdx.x, tid = threadIdx.x;
    int f = flagp[0];
    float v[4];
#pragma unroll
    for (int j = 0; j < 4; ++j) v[j] = dual1(x, (size_t)row * C_ + tid + j * 256, f);
    float s = 0.f, s2 = 0.f;
#pragma unroll
    for (int j = 0; j < 4; ++j) { s += v[j]; s2 += v[j] * v[j]; }
    float2 st = block_sum2(s, s2, rbuf, tid);
    float mu = st.x * (1.0f / C_), var = st.y * (1.0f / C_) - mu * mu, rs = rsqrtf(var + 1e-5f);
#pragma unroll
    for (int j = 0; j < 4; ++j) {
        int c = tid + j * 256;
        v[j] = (v[j] - mu) * rs * (float)g1[c] + (float)b1[c];
    }
    s = 0.f; s2 = 0.f;
#pragma unroll
    for (int j = 0; j < 4; ++j) { s += v[j]; s2 += v[j] * v[j]; }
    st = block_sum2(s, s2, rbuf, tid);
    mu = st.x * (1.0f / C_); var = st.y * (1.0f / C_) - mu * mu; rs = rsqrtf(var + 1e-5f);
#pragma unroll
    for (int j = 0; j < 4; ++j) {
        int c = tid + j * 256;
        xn[(size_t)row * C_ + c] = bf16((v[j] - mu) * rs * (float)g2[c] + (float)b2[c]);
    }
}

// ---------------- single layernorm (f32 in, bf16 out) ----------------
__global__ __launch_bounds__(256) void ln_single_kernel(const float* __restrict__ x,
                                                        const bf16* __restrict__ g, const bf16* __restrict__ b,
                                                        bf16* __restrict__ out) {
    __shared__ float2 rbuf[4];
    int row = blockIdx.x, tid = threadIdx.x;
    float v[4];
#pragma unroll
    for (int j = 0; j < 4; ++j) v[j] = x[(size_t)row * C_ + tid + j * 256];
    float s = 0.f, s2 = 0.f;
#pragma unroll
    for (int j = 0; j < 4; ++j) { s += v[j]; s2 += v[j] * v[j]; }
    float2 st = block_sum2(s, s2, rbuf, tid);
    float mu = st.x * (1.0f / C_), var = st.y * (1.0f / C_) - mu * mu, rs = rsqrtf(var + 1e-5f);
#pragma unroll
    for (int j = 0; j < 4; ++j) {
        int c = tid + j * 256;
        out[(size_t)row * C_ + c] = bf16((v[j] - mu) * rs * (float)g[c] + (float)b[c]);
    }
}

// ---------------- chunked linear recurrence ----------------
__global__ __launch_bounds__(256) void scan_pass1(const bf16* __restrict__ kb, const bf16* __restrict__ vb,
                                                  const bf16* __restrict__ td, float* __restrict__ carry) {
    int cb = blockIdx.x & 3;
    int chunk = (blockIdx.x >> 2) & (NC_ - 1);
    int b = blockIdx.x >> 8;
    int c = cb * 256 + threadIdx.x;
    float d = expf(-expf((float)td[c]));
    float h = 0.f;
    size_t base = ((size_t)b * T_ + (size_t)chunk * L_) * C_ + c;
#pragma unroll 4
    for (int j = 0; j < L_; ++j) {
        float kk = (float)kb[base + (size_t)j * C_];
        float vv = (float)vb[base + (size_t)j * C_];
        h = d * h + kk * vv;
    }
    carry[((size_t)(b * NC_ + chunk)) * C_ + c] = h;
}

__global__ __launch_bounds__(256) void scan_combine(const float* __restrict__ carry, float* __restrict__ hin,
                                                    const bf16* __restrict__ h0b, const bf16* __restrict__ td,
                                                    void* __restrict__ dout, const int* __restrict__ flagp) {
    int f = flagp[0];
    int cb = blockIdx.x & 3;
    int b = blockIdx.x >> 2;
    int c = cb * 256 + threadIdx.x;
    float d = expf(-expf((float)td[c]));
    float dL = powf(d, (float)L_);
    float run = (float)h0b[(size_t)b * C_ + c];
    for (int i = 0; i < NC_; ++i) {
        size_t o = ((size_t)(b * NC_ + i)) * C_ + c;
        hin[o] = run;
        run = dL * run + carry[o];
    }
    size_t oo = (size_t)B_ * T_ * C_ + (size_t)b * C_ + c;
    if (f) ((float*)dout)[oo] = run; else ((bf16*)dout)[oo] = bf16(run);
}

__global__ __launch_bounds__(256) void scan_pass2(bf16* __restrict__ qb, const bf16* __restrict__ kb,
                                                  const bf16* __restrict__ vb, const bf16* __restrict__ td,
                                                  const float* __restrict__ hin) {
    int cb = blockIdx.x & 3;
    int chunk = (blockIdx.x >> 2) & (NC_ - 1);
    int b = blockIdx.x >> 8;
    int c = cb * 256 + threadIdx.x;
    float d = expf(-expf((float)td[c]));
    float h = hin[((size_t)(b * NC_ + chunk)) * C_ + c];
    size_t base = ((size_t)b * T_ + (size_t)chunk * L_) * C_ + c;
#pragma unroll 4
    for (int j = 0; j < L_; ++j) {
        size_t o = base + (size_t)j * C_;
        float kk = (float)kb[o], vv = (float)vb[o], qq = (float)qb[o];
        h = d * h + kk * vv;
        float sg = 1.0f / (1.0f + expf(-qq));
        qb[o] = bf16(sg * h);
    }
}

// ---------------- bf16 MFMA GEMM core: async global_load_lds staging + swizzled LDS ----------------
// LDS slot (r,kc) holds global 16B chunk (r, kc ^ (r & (KC-1))) — lane-ordered for DMA,
// fragment ds_read_b128 lands on distinct banks (2-way max = free).
// RES: 0 none, 2 f32, 3 dual(flag). OUTM: 0 bf16, 1 f32, 2 f32+bf16, 3 dual(flag), 4 three bf16 planes.
template <int BM, int BN, int BK, int WM, int WN, int BIAS, int ACT, int RES, int OUTM, int AMIX>
__device__ __forceinline__ void gemm_core(const bf16* __restrict__ A, int lda, const bf16* __restrict__ BT,
                                          const bf16* __restrict__ bias, const void* __restrict__ res,
                                          void* __restrict__ out0, void* __restrict__ out1, void* __restrict__ out2,
                                          int M, int N, int K, const int* __restrict__ flagp) {
    constexpr int WGM = BM / WM;
    constexpr int MT = WM / 16, NT = WN / 16;
    constexpr int KC = BK / 8;                 // 16B chunks per tile-row
    constexpr int CHA = BM * KC, CHB = BN * KC;
    constexpr bool FBA = (CHA % 256 != 0) || (AMIX != 0);   // register-path fallback
    constexpr bool FBB = (CHB % 256 != 0);
    constexpr int RA = (CHA + 255) / 256, RB = (CHB + 255) / 256;
    constexpr int CW = WN / 4;
    constexpr int CHK = (CW >= 8) ? 8 : CW;
    constexpr int EPS = WN + 4;
    constexpr int SM_STAGE = (BM + BN) * BK * 2;
    constexpr int SM_EPI = 4 * 16 * EPS * 4;
    constexpr int SM = (SM_STAGE > SM_EPI) ? SM_STAGE : SM_EPI;
    static_assert(WGM * (BN / WN) == 4, "4 waves");
    __shared__ char smem[SM];
    u16* sA = (u16*)smem;                      // BM*BK u16, unpadded
    u16* sB = sA + BM * BK;
    const int tid = threadIdx.x, lane = tid & 63, wid = tid >> 6;
    const int wm = wid % WGM, wn = wid / WGM;
    const int l15 = lane & 15, lq = lane >> 4;
    const size_t m0 = (size_t)blockIdx.x * BM, n0 = (size_t)blockIdx.y * BN;
    const int KT = K / BK;
    const int f32f = (RES == 3 || OUTM == 3) ? flagp[0] : 0;

    // ---- DMA staging (lane-ordered LDS dst, swizzled global src) ----
    auto dmaA = [&](int kt) {
#pragma unroll
        for (int i = 0; i < RA; ++i) {
            int ci = tid + i * 256;
            int r = ci / KC, kc = ci % KC;
            const u16* gp = (const u16*)A + (m0 + r) * (size_t)lda + (size_t)kt * BK + (kc ^ (r & (KC - 1))) * 8;
            gld16(gp, sA + ci * 8);
        }
    };
    auto dmaB = [&](int kt) {
#pragma unroll
        for (int i = 0; i < RB; ++i) {
            int ci = tid + i * 256;
            int r = ci / KC, kc = ci % KC;
            const u16* gp = (const u16*)BT + (n0 + r) * (size_t)K + (size_t)kt * BK + (kc ^ (r & (KC - 1))) * 8;
            gld16(gp, sB + ci * 8);
        }
    };
    // ---- register-path fallback (AMIX mixing / non-divisible chunk counts) ----
    uint4 ra[FBA ? RA : 1], rb[FBB ? RB : 1];
    auto gloadA = [&](int kt) {
        if constexpr (FBA) {
#pragma unroll
            for (int i = 0; i < RA; ++i) {
                int ci = tid + i * 256;
                if ((CHA % 256 == 0) || ci < CHA) {
                    int r = ci / KC, kc = ci % KC;
                    const u16* gp = (const u16*)A + (m0 + r) * (size_t)lda + (size_t)kt * BK + kc * 8;
                    if constexpr (AMIX) {
                        uint4 c0 = *(const uint4*)gp;
                        uint4 p0 = make_uint4(0, 0, 0, 0);
                        if ((int)((m0 + r) % T_) != 0) p0 = *(const uint4*)(gp - lda);
                        bf16 cc[8], pp[8], oo[8];
                        *(uint4*)cc = c0; *(uint4*)pp = p0;
#pragma unroll
                        for (int j = 0; j < 8; ++j) oo[j] = bf16(0.5f * ((float)cc[j] + (float)pp[j]));
                        ra[i] = *(uint4*)oo;
                    } else {
                        ra[i] = *(const uint4*)gp;
                    }
                }
            }
        }
    };
    auto gloadB = [&](int kt) {
        if constexpr (FBB) {
#pragma unroll
            for (int i = 0; i < RB; ++i) {
                int ci = tid + i * 256;
                if ((CHB % 256 == 0) || ci < CHB) {
                    int r = ci / KC, kc = ci % KC;
                    rb[i] = *(const uint4*)((const u16*)BT + (n0 + r) * (size_t)K + (size_t)kt * BK + kc * 8);
                }
            }
        }
    };
    auto lstore = [&]() {
        if constexpr (FBA) {
#pragma unroll
            for (int i = 0; i < RA; ++i) {
                int ci = tid + i * 256;
                if ((CHA % 256 == 0) || ci < CHA) {
                    int r = ci / KC, kc = ci % KC;
                    *(uint4*)&sA[(r * KC + (kc ^ (r & (KC - 1)))) * 8] = ra[i];
                }
            }
        }
        if constexpr (FBB) {
#pragma unroll
            for (int i = 0; i < RB; ++i) {
                int ci = tid + i * 256;
                if ((CHB % 256 == 0) || ci < CHB) {
                    int r = ci / KC, kc = ci % KC;
                    *(uint4*)&sB[(r * KC + (kc ^ (r & (KC - 1)))) * 8] = rb[i];
                }
            }
        }
    };

    f32x4 acc[MT][NT];
#pragma unroll
    for (int i = 0; i < MT; ++i)
#pragma unroll
        for (int j = 0; j < NT; ++j) acc[i][j] = 0.0f;

    gloadA(0); gloadB(0);
    if constexpr (!FBA) dmaA(0);
    if constexpr (!FBB) dmaB(0);
    for (int kt = 0; kt < KT; ++kt) {
        lstore();
        if (kt + 1 < KT) { gloadA(kt + 1); gloadB(kt + 1); }
        __syncthreads();                       // drains DMA (vmcnt) + publishes lstore
        bf16x8 af[MT], bfr[NT];
#pragma unroll
        for (int i = 0; i < MT; ++i) {
            int r = wm * WM + i * 16 + l15;
            af[i] = *(const bf16x8*)&sA[(r * KC + (lq ^ (r & (KC - 1)))) * 8];
        }
#pragma unroll
        for (int j = 0; j < NT; ++j) {
            int r = wn * WN + j * 16 + l15;
            bfr[j] = *(const bf16x8*)&sB[(r * KC + (lq ^ (r & (KC - 1)))) * 8];
        }
#pragma unroll
        for (int i = 0; i < MT; ++i)
#pragma unroll
            for (int j = 0; j < NT; ++j)
                acc[i][j] = __builtin_amdgcn_mfma_f32_16x16x32_bf16(af[i], bfr[j], acc[i][j], 0, 0, 0);
        if (kt + 1 < KT) {
            __syncthreads();                   // LDS free before overwrite
            if constexpr (!FBA) dmaA(kt + 1);
            if constexpr (!FBB) dmaB(kt + 1);
        }
    }

    // ---- LDS-transposed epilogue ----
    __syncthreads();
    float* ep = (float*)smem + (size_t)wid * 16 * EPS;
    const int rrow = lane >> 2, seg = lane & 3;
    const size_t colbase = n0 + (size_t)wn * WN + (size_t)seg * CW;
    bf16* planep = nullptr;
    size_t colp = 0;
    if constexpr (OUTM == 4) {
        int plane = (int)(n0 >> 10);
        bf16* pls[3] = {(bf16*)out0, (bf16*)out1, (bf16*)out2};
        planep = pls[plane];
        colp = colbase - ((size_t)plane << 10);
    }
#pragma unroll
    for (int i = 0; i < MT; ++i) {
#pragma unroll
        for (int j = 0; j < NT; ++j)
#pragma unroll
            for (int r = 0; r < 4; ++r)
                ep[(4 * lq + r) * EPS + j * 16 + l15] = acc[i][j][r];
        const size_t gm = m0 + (size_t)wm * WM + i * 16 + rrow;
        const size_t gidx = gm * (size_t)N + colbase;
#pragma unroll
        for (int c0 = 0; c0 < CW; c0 += CHK) {
            alignas(16) float v[CHK];
            vcopy<CHK * 4>(v, ep + rrow * EPS + seg * CW + c0);
            if constexpr (BIAS) {
                alignas(16) bf16 bt[CHK];
                vcopy<CHK * 2>(bt, bias + colbase + c0);
#pragma unroll
                for (int t = 0; t < CHK; ++t) v[t] += (float)bt[t];
            }
            if constexpr (ACT == 1) {
#pragma unroll
                for (int t = 0; t < CHK; ++t) v[t] = gelu_tanh(v[t]);
            }
            if constexpr (RES == 2) {
                alignas(16) float rv[CHK];
                vcopy<CHK * 4>(rv, (const float*)res + gidx + c0);
#pragma unroll
                for (int t = 0; t < CHK; ++t) v[t] += rv[t];
            }
            if constexpr (RES == 3) {
                if (f32f) {
                    alignas(16) float rv[CHK];
                    vcopy<CHK * 4>(rv, (const float*)res + gidx + c0);
#pragma unroll
                    for (int t = 0; t < CHK; ++t) v[t] += rv[t];
                } else {
                    alignas(16) bf16 rv[CHK];
                    vcopy<CHK * 2>(rv, (const bf16*)res + gidx + c0);
#pragma unroll
                    for (int t = 0; t < CHK; ++t) v[t] += (float)rv[t];
                }
            }
            if constexpr (OUTM == 0 || OUTM == 2 || OUTM == 4) {
                alignas(16) bf16 ob[CHK];
#pragma unroll
                for (int t = 0; t < CHK; ++t) ob[t] = bf16(v[t]);
                if constexpr (OUTM == 0) vcopy<CHK * 2>((bf16*)out0 + gidx + c0, ob);
                if constexpr (OUTM == 2) {
                    vcopy<CHK * 4>((float*)out0 + gidx + c0, v);
                    vcopy<CHK * 2>((bf16*)out1 + gidx + c0, ob);
                }
                if constexpr (OUTM == 4) vcopy<CHK * 2>(planep + (gm << 10) + colp + c0, ob);
            }
            if constexpr (OUTM == 1) vcopy<CHK * 4>((float*)out0 + gidx + c0, v);
            if constexpr (OUTM == 3) {
                if (f32f) {
                    vcopy<CHK * 4>((float*)out0 + gidx + c0, v);
                } else {
                    alignas(16) bf16 ob[CHK];
#pragma unroll
                    for (int t = 0; t < CHK; ++t) ob[t] = bf16(v[t]);
                    vcopy<CHK * 2>((bf16*)out0 + gidx + c0, ob);
                }
            }
        }
    }
}

#define GEMM_KERNEL(NAME, BM, BN, BK, WM, WN, BIAS, ACT, RES, OUTM, AMIX)                                     \
    __global__ __launch_bounds__(256) void NAME(const bf16* A, int lda, const bf16* BT, const bf16* bias,     \
                                                const void* res, void* out0, void* out1, void* out2, int M,   \
                                                int N, int K, const int* flagp) {                             \
        gemm_core<BM, BN, BK, WM, WN, BIAS, ACT, RES, OUTM, AMIX>(A, lda, BT, bias, res, out0, out1, out2,    \
                                                                  M, N, K, flagp);                            \
    }

GEMM_KERNEL(g_down,   128, 64, 32, 64, 32, 0, 0, 0, 0, 1)   // mix @ [qu|ku|vu] -> tq (M x 192)
GEMM_KERNEL(g_attn,   128, 128, 32, 64, 64, 1, 0, 3, 1, 0)  // ys @ out_w + out_b + x -> x1f
GEMM_KERNEL(g_ffn1,   128, 128, 32, 64, 64, 1, 1, 0, 0, 0)  // gelu(h2 @ w1 + b1) -> mid
GEMM_KERNEL(g_ffn2,   128, 128, 32, 64, 64, 1, 0, 2, 2, 0)  // mid @ w2 + b2 + x1f -> x1f, x2b
GEMM_KERNEL(g_addown, 64, 32, 32, 32, 16, 1, 1, 0, 0, 0)    // gelu(x2 @ ad_w + ad_b) -> adt
GEMM_KERNEL(g_adup,   128, 128, 32, 64, 64, 1, 0, 2, 3, 0)  // adt @ au_w + au_b + x1f -> d_out

// fused up-projection: block-diagonal A, B = [qvT;kvT;vvT]
__global__ __launch_bounds__(256) void g_upf(const bf16* A, int lda, const bf16* BT, const bf16* bias,
                                             const void* res, void* out0, void* out1, void* out2, int M,
                                             int N, int K, const int* flagp) {
    const bf16* Ap = A + (size_t)(blockIdx.y >> 3) * 64;
    gemm_core<128, 128, 32, 64, 64, 0, 0, 0, 4, 0>(Ap, lda, BT, bias, res, out0, out1, out2, M, N, K, flagp);
}

// ---------------- host side ----------------
extern "C" void kernel_launch(void* const* d_in, const int* in_sizes, int n_in,
                              void* d_out, int out_size, void* d_ws, size_t ws_size,
                              hipStream_t stream) {
    (void)in_sizes; (void)n_in; (void)out_size;
    const void* x     = d_in[0];
    const void* h0    = d_in[1];
    const void* ln1_g = d_in[2];
    const void* ln1_b = d_in[3];
    const void* tm_g  = d_in[4];
    const void* tm_b  = d_in[5];
    const void* qu    = d_in[6];
    const void* qv    = d_in[7];
    const void* ku    = d_in[8];
    const void* kv    = d_in[9];
    const void* vu    = d_in[10];
    const void* vv    = d_in[11];
    const void* td    = d_in[12];
    const void* out_w = d_in[13];
    const void* out_b = d_in[14];
    const void* ln2_g = d_in[15];
    const void* ln2_b = d_in[16];
    const void* ffn_w1 = d_in[17];
    const void* ffn_b1 = d_in[18];
    const void* ffn_w2 = d_in[19];
    const void* ffn_b2 = d_in[20];
    const void* ad_w  = d_in[21];
    const void* ad_b  = d_in[22];
    const void* au_w  = d_in[23];
    const void* au_b  = d_in[24];

    char* ws = (char*)d_ws;
    size_t off = 0;
    auto alloc = [&](size_t bytes) -> void* {
        void* p = ws + off;
        off += (bytes + 255) & ~(size_t)255;
        return p;
    };
    const size_t BTC = (size_t)B_ * T_ * C_;
    bf16* uT  = (bf16*)alloc((size_t)192 * C_ * 2);
    bf16* vT3 = (bf16*)alloc((size_t)3072 * R_ * 2);
    bf16* owT = (bf16*)alloc((size_t)C_ * C_ * 2);
    bf16* w1T = (bf16*)alloc((size_t)C_ * FF_ * 2);
    bf16* w2T = (bf16*)alloc((size_t)C_ * FF_ * 2);
    bf16* adT = (bf16*)alloc((size_t)C_ * AR_ * 2);
    bf16* auT = (bf16*)alloc((size_t)C_ * AR_ * 2);
    bf16* c_ln1g = (bf16*)alloc(C_ * 2);
    bf16* c_ln1b = (bf16*)alloc(C_ * 2);
    bf16* c_tmg  = (bf16*)alloc(C_ * 2);
    bf16* c_tmb  = (bf16*)alloc(C_ * 2);
    bf16* c_td   = (bf16*)alloc(C_ * 2);
    bf16* c_outb = (bf16*)alloc(C_ * 2);
    bf16* c_ln2g = (bf16*)alloc(C_ * 2);
    bf16* c_ln2b = (bf16*)alloc(C_ * 2);
    bf16* c_fb1  = (bf16*)alloc(FF_ * 2);
    bf16* c_fb2  = (bf16*)alloc(C_ * 2);
    bf16* c_adb  = (bf16*)alloc(AR_ * 2);
    bf16* c_aub  = (bf16*)alloc(C_ * 2);
    bf16* c_h0   = (bf16*)alloc((size_t)B_ * C_ * 2);
    int*  flag   = (int*)alloc(256);
    bf16* xn = (bf16*)alloc(BTC * 2);
    bf16* vb = (bf16*)alloc(BTC * 2);
    bf16* qb = (bf16*)alloc(BTC * 2);
    bf16* kb = (bf16*)alloc(BTC * 2);
    bf16* tq = (bf16*)alloc((size_t)M_ * 192 * 2);
    float* carry = (float*)alloc((size_t)B_ * NC_ * C_ * 4);
    float* hin   = (float*)alloc((size_t)B_ * NC_ * C_ * 4);
    float* x1f = (float*)xn;   // aliases xn+vb (dead by then)

    const size_t midb_bytes = (size_t)M_ * FF_ * 2;
    bool big = ws_size >= off + midb_bytes + (1u << 20);
    bf16* midb = big ? (bf16*)alloc(midb_bytes) : qb;
    const int nchunk = big ? 1 : 4;
    const int crows = M_ / nchunk;

    detect_kernel<<<1, 256, 0, stream>>>((const u32*)x, flag);

    PrepArgs pa;
    const void* tsrc[11] = {qu, ku, vu, qv, kv, vv, out_w, ffn_w1, ffn_w2, ad_w, au_w};
    void* tdst[11] = {uT, uT + (size_t)64 * C_, uT + (size_t)128 * C_,
                      vT3, vT3 + (size_t)1024 * R_, vT3 + (size_t)2048 * R_, owT, w1T, w2T, adT, auT};
    int tK[11] = {C_, C_, C_, R_, R_, R_, C_, C_, FF_, C_, AR_};
    int tN[11] = {R_, R_, R_, C_, C_, C_, C_, FF_, C_, AR_, C_};
    const void* vsrc[13] = {ln1_g, ln1_b, tm_g, tm_b, td, out_b, ln2_g, ln2_b, ffn_b1, ffn_b2, ad_b, au_b, h0};
    void* vdst[13] = {c_ln1g, c_ln1b, c_tmg, c_tmb, c_td, c_outb, c_ln2g, c_ln2b, c_fb1, c_fb2, c_adb, c_aub, c_h0};
    int vn[13] = {C_, C_, C_, C_, C_, C_, C_, C_, FF_, C_, AR_, C_, B_ * C_};
    int nb = 0;
    for (int i = 0; i < 11; ++i) {
        pa.src[i] = tsrc[i]; pa.dst[i] = tdst[i]; pa.K[i] = tK[i]; pa.N[i] = tN[i];
        pa.start[i] = nb;
        nb += ((tN[i] + 31) / 32) * ((tK[i] + 31) / 32);
    }
    for (int i = 0; i < 13; ++i) {
        pa.src[11 + i] = vsrc[i]; pa.dst[11 + i] = vdst[i]; pa.K[11 + i] = 0; pa.N[11 + i] = vn[i];
        pa.start[11 + i] = nb;
        nb += 1;
    }
    pa.start[24] = nb;
    pa.start[25] = nb;
    pa.n_tr = 11;
    weight_prep<<<nb, 256, 0, stream>>>(pa, flag);

    ln2x_kernel<<<M_, 256, 0, stream>>>(x, flag, c_ln1g, c_ln1b, c_tmg, c_tmb, xn);

    g_down<<<dim3(M_ / 128, 3), 256, 0, stream>>>(xn, C_, uT, nullptr, nullptr, tq, nullptr, nullptr, M_, 192, C_, flag);
    g_upf<<<dim3(M_ / 128, 24), 256, 0, stream>>>(tq, 192, vT3, nullptr, nullptr, qb, kb, vb, M_, 3072, R_, flag);

    scan_pass1<<<B_ * NC_ * (C_ / 256), 256, 0, stream>>>(kb, vb, c_td, carry);
    scan_combine<<<B_ * (C_ / 256), 256, 0, stream>>>(carry, hin, c_h0, c_td, d_out, flag);
    scan_pass2<<<B_ * NC_ * (C_ / 256), 256, 0, stream>>>(qb, kb, vb, c_td, hin);

    g_attn<<<dim3(M_ / 128, C_ / 128), 256, 0, stream>>>(qb, C_, owT, c_outb, x, x1f, nullptr, nullptr, M_, C_, C_, flag);

    ln_single_kernel<<<M_, 256, 0, stream>>>(x1f, c_ln2g, c_ln2b, kb);
    for (int c = 0; c < nchunk; ++c) {
        bf16* h2c = kb + (size_t)c * crows * C_;
        bf16* mid = big ? midb + (size_t)c * crows * FF_ : midb;
        float* x1c = x1f + (size_t)c * crows * C_;
        g_ffn1<<<dim3(crows / 128, FF_ / 128), 256, 0, stream>>>(h2c, C_, w1T, c_fb1, nullptr, mid, nullptr, nullptr, crows, FF_, C_, flag);
        g_ffn2<<<dim3(crows / 128, C_ / 128), 256, 0, stream>>>(mid, FF_, w2T, c_fb2, x1c, x1c, h2c, nullptr, crows, C_, FF_, flag);
    }

    g_addown<<<dim3(M_ / 64, 1), 256, 0, stream>>>(kb, C_, adT, c_adb, nullptr, tq, nullptr, nullptr, M_, AR_, C_, flag);
    g_adup<<<dim3(M_ / 128, C_ / 128), 256, 0, stream>>>(tq, AR_, auT, c_aub, x1f, d_out, nullptr, nullptr, M_, C_, AR_, flag);
}